// Round 1
// baseline (195.087 us; speedup 1.0000x reference)
//
#include <hip/hip_runtime.h>
#include <hip/hip_bf16.h>
#include <cstdint>
#include <cstddef>

#define DIM   1024
#define INTER 1024
#define NT    2048      // tokens
#define HROWS 6144      // 4096 routed pair slots + 2048 shared rows

typedef __attribute__((ext_vector_type(4))) float  f32x4;
typedef __attribute__((ext_vector_type(8))) short  s16x8;
typedef __attribute__((ext_vector_type(8))) unsigned short u16x8;

// workspace layout (bytes)
#define WS_CNT    0u
#define WS_SLOT   256u
#define WS_WT     65792u
#define WS_XB     131584u     // [2048][1024] bf16  (4 MB)
#define WS_H      4325888u    // [6144][1024] bf16  (12.6 MB)
#define WS_W1T    16908800u   // [8][1024][1024] bf16 (16 MB)
#define WS_W3T    33686016u
#define WS_W2T    50463232u
#define WS_SW1T   67240448u
#define WS_SW3T   69337600u
#define WS_SW2T   71434752u
#define WS_NEED   73531904u

__device__ __forceinline__ unsigned short f2bf(float f) {
    unsigned int u = __float_as_uint(f);
    return (unsigned short)((u + 0x7fffu + ((u >> 16) & 1u)) >> 16);
}

__device__ __forceinline__ void cp16(const void* g, void* l) {
    __builtin_amdgcn_global_load_lds((const __attribute__((address_space(1))) void*)g,
                                     (__attribute__((address_space(3))) void*)l, 16, 0, 0);
}

// ---------------- weight transpose + fp32->bf16 ----------------
// src [1024][1024] f32 row-major -> dst bf16 with dst[c][r] = src[r][c]
__global__ __launch_bounds__(256) void kconv_t(
    const float* __restrict__ w1, const float* __restrict__ w2, const float* __restrict__ w3,
    const float* __restrict__ sw1, const float* __restrict__ sw2, const float* __restrict__ sw3,
    unsigned short* __restrict__ w1t, unsigned short* __restrict__ w3t, unsigned short* __restrict__ w2t,
    unsigned short* __restrict__ sw1t, unsigned short* __restrict__ sw3t, unsigned short* __restrict__ sw2t)
{
    int z = blockIdx.z;
    const float* src; unsigned short* dst;
    if (z < 8)        { src = w1  + (size_t)z      * DIM * INTER; dst = w1t  + (size_t)z      * DIM * INTER; }
    else if (z < 16)  { src = w3  + (size_t)(z-8)  * DIM * INTER; dst = w3t  + (size_t)(z-8)  * DIM * INTER; }
    else if (z < 24)  { src = w2  + (size_t)(z-16) * DIM * INTER; dst = w2t  + (size_t)(z-16) * DIM * INTER; }
    else if (z == 24) { src = sw1; dst = sw1t; }
    else if (z == 25) { src = sw3; dst = sw3t; }
    else              { src = sw2; dst = sw2t; }

    __shared__ float tile[64][65];
    int tid = threadIdx.x;
    int r0 = blockIdx.y * 64, c0 = blockIdx.x * 64;
    int lr = tid >> 2, lcg = (tid & 3) * 16;
    const f32x4* srow = (const f32x4*)(src + (size_t)(r0 + lr) * 1024 + c0 + lcg);
    #pragma unroll
    for (int q = 0; q < 4; ++q) {
        f32x4 v = srow[q];
        #pragma unroll
        for (int j = 0; j < 4; ++j) tile[lr][lcg + q*4 + j] = v[j];
    }
    __syncthreads();
    int dc = tid >> 2, dkg = (tid & 3) * 16;
    u16x8 o0, o1;
    #pragma unroll
    for (int j = 0; j < 8; ++j) o0[j] = f2bf(tile[dkg + j][dc]);
    #pragma unroll
    for (int j = 0; j < 8; ++j) o1[j] = f2bf(tile[dkg + 8 + j][dc]);
    u16x8* drow = (u16x8*)(dst + (size_t)(c0 + dc) * 1024 + r0 + dkg);
    drow[0] = o0; drow[1] = o1;
}

// ---------------- x fp32 -> bf16 ----------------
__global__ __launch_bounds__(256) void kconv_x(const float* __restrict__ x, unsigned short* __restrict__ xb)
{
    int gid = blockIdx.x * 256 + threadIdx.x;
    const f32x4* s = (const f32x4*)x + (size_t)gid * 2;
    f32x4 a = s[0], b = s[1];
    u16x8 o;
    #pragma unroll
    for (int j = 0; j < 4; ++j) o[j] = f2bf(a[j]);
    #pragma unroll
    for (int j = 0; j < 4; ++j) o[4+j] = f2bf(b[j]);
    ((u16x8*)xb)[gid] = o;
}

// ---------------- gate: softmax + top2 + scatter ----------------
__global__ __launch_bounds__(256) void kgate(const float* __restrict__ x, const float* __restrict__ gw,
                                             int* __restrict__ cnt, int* __restrict__ slotlist,
                                             float* __restrict__ wtlist)
{
    int wid = threadIdx.x >> 6, lane = threadIdx.x & 63;
    int t = blockIdx.x * 4 + wid;
    const f32x4* xv = (const f32x4*)(x + (size_t)t * DIM + lane * 16);
    f32x4 xs0 = xv[0], xs1 = xv[1], xs2 = xv[2], xs3 = xv[3];
    float xr[16];
    #pragma unroll
    for (int j = 0; j < 4; ++j) { xr[j] = xs0[j]; xr[4+j] = xs1[j]; xr[8+j] = xs2[j]; xr[12+j] = xs3[j]; }

    float acc[8] = {0.f,0.f,0.f,0.f,0.f,0.f,0.f,0.f};
    #pragma unroll
    for (int i = 0; i < 16; ++i) {
        const f32x4* g = (const f32x4*)(gw + (size_t)(lane * 16 + i) * 8);
        f32x4 g0 = g[0], g1 = g[1];
        float xvv = xr[i];
        acc[0] += xvv * g0[0]; acc[1] += xvv * g0[1]; acc[2] += xvv * g0[2]; acc[3] += xvv * g0[3];
        acc[4] += xvv * g1[0]; acc[5] += xvv * g1[1]; acc[6] += xvv * g1[2]; acc[7] += xvv * g1[3];
    }
    #pragma unroll
    for (int e = 0; e < 8; ++e) {
        float v = acc[e];
        v += __shfl_xor(v, 1);  v += __shfl_xor(v, 2);  v += __shfl_xor(v, 4);
        v += __shfl_xor(v, 8);  v += __shfl_xor(v, 16); v += __shfl_xor(v, 32);
        acc[e] = v;
    }
    float mx = acc[0];
    #pragma unroll
    for (int e = 1; e < 8; ++e) mx = fmaxf(mx, acc[e]);
    float p[8]; float se = 0.f;
    #pragma unroll
    for (int e = 0; e < 8; ++e) { p[e] = expf(acc[e] - mx); se += p[e]; }
    float inv = 1.0f / se;
    // top-1 / top-2, lowest index wins ties (matches jax.lax.top_k)
    int i0 = 0; float b0 = p[0];
    #pragma unroll
    for (int e = 1; e < 8; ++e) if (p[e] > b0) { b0 = p[e]; i0 = e; }
    int i1 = -1; float b1 = -1.f;
    #pragma unroll
    for (int e = 0; e < 8; ++e) if (e != i0 && p[e] > b1) { b1 = p[e]; i1 = e; }
    if (lane == 0) {
        int pos = atomicAdd(&cnt[i0], 1);
        slotlist[i0 * NT + pos] = t * 2;
        wtlist [i0 * NT + pos] = b0 * inv;
        pos = atomicAdd(&cnt[i1], 1);
        slotlist[i1 * NT + pos] = t * 2 + 1;
        wtlist [i1 * NT + pos] = b1 * inv;
    }
}

// ---------------- GEMM1: h = silu(X W1) * (X W3), gathered rows ----------------
// tile BM=128 BN=64 BK=64; 4 waves 2x2, wave tile 64x32
__global__ __launch_bounds__(256) void kgemm1(
    const unsigned short* __restrict__ xb,
    const unsigned short* __restrict__ w1t, const unsigned short* __restrict__ w3t,
    const unsigned short* __restrict__ sw1t, const unsigned short* __restrict__ sw3t,
    const int* __restrict__ cnt, const int* __restrict__ slotlist,
    unsigned short* __restrict__ hbuf)
{
    int e = blockIdx.z;
    int m0 = blockIdx.y * 128;
    int n0 = blockIdx.x * 64;
    int n_rows = (e < 8) ? cnt[e] : NT;
    if (m0 >= n_rows) return;
    int rm = min(128, n_rows - m0);

    const unsigned short* b1p = (e < 8) ? (w1t + (size_t)e * DIM * INTER) : sw1t;
    const unsigned short* b3p = (e < 8) ? (w3t + (size_t)e * DIM * INTER) : sw3t;

    __shared__ __align__(16) short As[128 * 64];
    __shared__ __align__(16) short B1s[64 * 64];
    __shared__ __align__(16) short B3s[64 * 64];
    __shared__ int rowTok[128];
    __shared__ int rowSlot[128];

    int tid = threadIdx.x;
    if (tid < 128) {
        int r = m0 + min(tid, rm - 1);
        int slot, tok;
        if (e < 8) { slot = slotlist[e * NT + r]; tok = slot >> 1; }
        else       { tok = r; slot = 4096 + r; }
        rowTok[tid] = tok;
        rowSlot[tid] = slot;
    }
    __syncthreads();

    int wid = tid >> 6, lane = tid & 63;
    int wr = wid >> 1, wc = wid & 1;

    const char* gA[4];
    #pragma unroll
    for (int q = 0; q < 4; ++q) {
        int row = (q * 4 + wid) * 8 + (lane >> 3);
        gA[q] = (const char*)(xb + (size_t)rowTok[row] * DIM) + (lane & 7) * 16;
    }
    const char* gB1[2]; const char* gB3[2];
    #pragma unroll
    for (int q = 0; q < 2; ++q) {
        int nrow = (q * 4 + wid) * 8 + (lane >> 3);
        gB1[q] = (const char*)(b1p + (size_t)(n0 + nrow) * DIM) + (lane & 7) * 16;
        gB3[q] = (const char*)(b3p + (size_t)(n0 + nrow) * DIM) + (lane & 7) * 16;
    }

    f32x4 acc1[4][2], acc3[4][2];
    #pragma unroll
    for (int m = 0; m < 4; ++m)
        #pragma unroll
        for (int n = 0; n < 2; ++n) { acc1[m][n] = (f32x4){0.f,0.f,0.f,0.f}; acc3[m][n] = (f32x4){0.f,0.f,0.f,0.f}; }

    for (int k0 = 0; k0 < DIM; k0 += 64) {
        #pragma unroll
        for (int q = 0; q < 4; ++q) cp16(gA[q] + (size_t)k0 * 2, &As[(q * 4 + wid) * 512]);
        #pragma unroll
        for (int q = 0; q < 2; ++q) {
            cp16(gB1[q] + (size_t)k0 * 2, &B1s[(q * 4 + wid) * 512]);
            cp16(gB3[q] + (size_t)k0 * 2, &B3s[(q * 4 + wid) * 512]);
        }
        __syncthreads();
        #pragma unroll
        for (int ks = 0; ks < 2; ++ks) {
            s16x8 a[4];
            #pragma unroll
            for (int m = 0; m < 4; ++m) {
                int row = wr * 64 + m * 16 + (lane & 15);
                a[m] = *(const s16x8*)&As[row * 64 + ks * 32 + (lane >> 4) * 8];
            }
            #pragma unroll
            for (int n = 0; n < 2; ++n) {
                int col = wc * 32 + n * 16 + (lane & 15);
                s16x8 b1 = *(const s16x8*)&B1s[col * 64 + ks * 32 + (lane >> 4) * 8];
                s16x8 b3 = *(const s16x8*)&B3s[col * 64 + ks * 32 + (lane >> 4) * 8];
                #pragma unroll
                for (int m = 0; m < 4; ++m) {
                    acc1[m][n] = __builtin_amdgcn_mfma_f32_16x16x32_bf16(a[m], b1, acc1[m][n], 0, 0, 0);
                    acc3[m][n] = __builtin_amdgcn_mfma_f32_16x16x32_bf16(a[m], b3, acc3[m][n], 0, 0, 0);
                }
            }
        }
        __syncthreads();
    }

    #pragma unroll
    for (int m = 0; m < 4; ++m) {
        int rbase = wr * 64 + m * 16 + (lane >> 4) * 4;
        #pragma unroll
        for (int r = 0; r < 4; ++r) {
            int row = rbase + r;
            if (row < rm) {
                int hrow = rowSlot[row];
                #pragma unroll
                for (int n = 0; n < 2; ++n) {
                    float v1 = acc1[m][n][r], v3 = acc3[m][n][r];
                    float hv = (v1 / (1.0f + __expf(-v1))) * v3;
                    int col = n0 + wc * 32 + n * 16 + (lane & 15);
                    hbuf[(size_t)hrow * INTER + col] = f2bf(hv);
                }
            }
        }
    }
}

// ---------------- GEMM2: out += wt * (h W2), scatter by token ----------------
__global__ __launch_bounds__(256) void kgemm2(
    const unsigned short* __restrict__ hbuf,
    const unsigned short* __restrict__ w2t, const unsigned short* __restrict__ sw2t,
    const int* __restrict__ cnt, const int* __restrict__ slotlist, const float* __restrict__ wtlist,
    float* __restrict__ out)
{
    int e = blockIdx.z;
    int m0 = blockIdx.y * 128;
    int n0 = blockIdx.x * 64;
    int n_rows = (e < 8) ? cnt[e] : NT;
    if (m0 >= n_rows) return;
    int rm = min(128, n_rows - m0);
    const unsigned short* bp = (e < 8) ? (w2t + (size_t)e * DIM * INTER) : sw2t;

    __shared__ __align__(16) short As[128 * 64];
    __shared__ __align__(16) short Bs[64 * 64];
    __shared__ int rowTok[128];
    __shared__ int rowH[128];
    __shared__ float rowW[128];

    int tid = threadIdx.x;
    if (tid < 128) {
        int r = m0 + min(tid, rm - 1);
        if (e < 8) { int slot = slotlist[e * NT + r]; rowH[tid] = slot; rowTok[tid] = slot >> 1; rowW[tid] = wtlist[e * NT + r]; }
        else       { rowH[tid] = 4096 + r; rowTok[tid] = r; rowW[tid] = 1.0f; }
    }
    __syncthreads();

    int wid = tid >> 6, lane = tid & 63;
    int wr = wid >> 1, wc = wid & 1;

    const char* gA[4];
    #pragma unroll
    for (int q = 0; q < 4; ++q) {
        int row = (q * 4 + wid) * 8 + (lane >> 3);
        gA[q] = (const char*)(hbuf + (size_t)rowH[row] * INTER) + (lane & 7) * 16;
    }
    const char* gB[2];
    #pragma unroll
    for (int q = 0; q < 2; ++q) {
        int nrow = (q * 4 + wid) * 8 + (lane >> 3);
        gB[q] = (const char*)(bp + (size_t)(n0 + nrow) * INTER) + (lane & 7) * 16;
    }

    f32x4 acc[4][2];
    #pragma unroll
    for (int m = 0; m < 4; ++m)
        #pragma unroll
        for (int n = 0; n < 2; ++n) acc[m][n] = (f32x4){0.f,0.f,0.f,0.f};

    for (int k0 = 0; k0 < INTER; k0 += 64) {
        #pragma unroll
        for (int q = 0; q < 4; ++q) cp16(gA[q] + (size_t)k0 * 2, &As[(q * 4 + wid) * 512]);
        #pragma unroll
        for (int q = 0; q < 2; ++q) cp16(gB[q] + (size_t)k0 * 2, &Bs[(q * 4 + wid) * 512]);
        __syncthreads();
        #pragma unroll
        for (int ks = 0; ks < 2; ++ks) {
            s16x8 a[4];
            #pragma unroll
            for (int m = 0; m < 4; ++m) {
                int row = wr * 64 + m * 16 + (lane & 15);
                a[m] = *(const s16x8*)&As[row * 64 + ks * 32 + (lane >> 4) * 8];
            }
            #pragma unroll
            for (int n = 0; n < 2; ++n) {
                int col = wc * 32 + n * 16 + (lane & 15);
                s16x8 b = *(const s16x8*)&Bs[col * 64 + ks * 32 + (lane >> 4) * 8];
                #pragma unroll
                for (int m = 0; m < 4; ++m)
                    acc[m][n] = __builtin_amdgcn_mfma_f32_16x16x32_bf16(a[m], b, acc[m][n], 0, 0, 0);
            }
        }
        __syncthreads();
    }

    #pragma unroll
    for (int m = 0; m < 4; ++m) {
        int rbase = wr * 64 + m * 16 + (lane >> 4) * 4;
        #pragma unroll
        for (int r = 0; r < 4; ++r) {
            int row = rbase + r;
            if (row < rm) {
                float wgt = rowW[row];
                int tok = rowTok[row];
                #pragma unroll
                for (int n = 0; n < 2; ++n) {
                    int col = n0 + wc * 32 + n * 16 + (lane & 15);
                    atomicAdd(&out[(size_t)tok * DIM + col], acc[m][n][r] * wgt);
                }
            }
        }
    }
}

extern "C" void kernel_launch(void* const* d_in, const int* in_sizes, int n_in,
                              void* d_out, int out_size, void* d_ws, size_t ws_size,
                              hipStream_t stream) {
    const float* x      = (const float*)d_in[0];
    const float* gate_w = (const float*)d_in[1];
    const float* w1     = (const float*)d_in[2];
    const float* w2     = (const float*)d_in[3];
    const float* w3     = (const float*)d_in[4];
    const float* sw1    = (const float*)d_in[5];
    const float* sw2    = (const float*)d_in[6];
    const float* sw3    = (const float*)d_in[7];
    float* out = (float*)d_out;

    if (ws_size < (size_t)WS_NEED) return;  // fail loudly via poisoned output

    char* ws = (char*)d_ws;
    int*            cnt      = (int*)(ws + WS_CNT);
    int*            slotlist = (int*)(ws + WS_SLOT);
    float*          wtlist   = (float*)(ws + WS_WT);
    unsigned short* xb       = (unsigned short*)(ws + WS_XB);
    unsigned short* hbuf     = (unsigned short*)(ws + WS_H);
    unsigned short* w1t      = (unsigned short*)(ws + WS_W1T);
    unsigned short* w3t      = (unsigned short*)(ws + WS_W3T);
    unsigned short* w2t      = (unsigned short*)(ws + WS_W2T);
    unsigned short* sw1t     = (unsigned short*)(ws + WS_SW1T);
    unsigned short* sw3t     = (unsigned short*)(ws + WS_SW3T);
    unsigned short* sw2t     = (unsigned short*)(ws + WS_SW2T);

    hipMemsetAsync(cnt, 0, 256, stream);
    hipMemsetAsync(d_out, 0, (size_t)out_size * sizeof(float), stream);

    kconv_t<<<dim3(16, 16, 27), 256, 0, stream>>>(w1, w2, w3, sw1, sw2, sw3,
                                                  w1t, w3t, w2t, sw1t, sw3t, sw2t);
    kconv_x<<<dim3(1024), 256, 0, stream>>>(x, xb);
    kgate<<<dim3(NT / 4), 256, 0, stream>>>(x, gate_w, cnt, slotlist, wtlist);
    kgemm1<<<dim3(16, 16, 9), 256, 0, stream>>>(xb, w1t, w3t, sw1t, sw3t, cnt, slotlist, hbuf);
    kgemm2<<<dim3(16, 16, 9), 256, 0, stream>>>(hbuf, w2t, sw2t, cnt, slotlist, wtlist, out);
}

// Round 3
// 181.584 us; speedup vs baseline: 1.0744x; 1.0744x over previous
//
#include <hip/hip_runtime.h>
#include <hip/hip_bf16.h>
#include <cstdint>
#include <cstddef>

#define DIM   1024
#define INTER 1024
#define NT    2048      // tokens
#define HROWS 6144      // 4096 routed pair slots + 2048 shared rows

typedef __attribute__((ext_vector_type(4))) float  f32x4;
typedef __attribute__((ext_vector_type(8))) short  s16x8;
typedef __attribute__((ext_vector_type(8))) unsigned short u16x8;

// workspace layout (bytes)
#define WS_CNT    0u
#define WS_SLOT   256u
#define WS_WT     65792u
#define WS_XB     131584u     // [2048][1024] bf16  (4 MB)
#define WS_H      4325888u    // [6144][1024] bf16  (12.6 MB)
#define WS_W1T    16908800u   // [8][1024][1024] bf16 (16 MB)
#define WS_W3T    33686016u
#define WS_W2T    50463232u
#define WS_SW1T   67240448u
#define WS_SW3T   69337600u
#define WS_SW2T   71434752u
#define WS_NEED   73531904u

__device__ __forceinline__ unsigned short f2bf(float f) {
    unsigned int u = __float_as_uint(f);
    return (unsigned short)((u + 0x7fffu + ((u >> 16) & 1u)) >> 16);
}

__device__ __forceinline__ void cp16(const void* g, void* l) {
    __builtin_amdgcn_global_load_lds((const __attribute__((address_space(1))) void*)g,
                                     (__attribute__((address_space(3))) void*)l, 16, 0, 0);
}

// ---------------- weight transpose + fp32->bf16 ----------------
// src [1024][1024] f32 row-major -> dst bf16 with dst[c][r] = src[r][c]
__global__ __launch_bounds__(256) void kconv_t(
    const float* __restrict__ w1, const float* __restrict__ w2, const float* __restrict__ w3,
    const float* __restrict__ sw1, const float* __restrict__ sw2, const float* __restrict__ sw3,
    unsigned short* __restrict__ w1t, unsigned short* __restrict__ w3t, unsigned short* __restrict__ w2t,
    unsigned short* __restrict__ sw1t, unsigned short* __restrict__ sw3t, unsigned short* __restrict__ sw2t)
{
    int z = blockIdx.z;
    const float* src; unsigned short* dst;
    if (z < 8)        { src = w1  + (size_t)z      * DIM * INTER; dst = w1t  + (size_t)z      * DIM * INTER; }
    else if (z < 16)  { src = w3  + (size_t)(z-8)  * DIM * INTER; dst = w3t  + (size_t)(z-8)  * DIM * INTER; }
    else if (z < 24)  { src = w2  + (size_t)(z-16) * DIM * INTER; dst = w2t  + (size_t)(z-16) * DIM * INTER; }
    else if (z == 24) { src = sw1; dst = sw1t; }
    else if (z == 25) { src = sw3; dst = sw3t; }
    else              { src = sw2; dst = sw2t; }

    __shared__ float tile[64][65];
    int tid = threadIdx.x;
    int r0 = blockIdx.y * 64, c0 = blockIdx.x * 64;
    int lr = tid >> 2, lcg = (tid & 3) * 16;
    const f32x4* srow = (const f32x4*)(src + (size_t)(r0 + lr) * 1024 + c0 + lcg);
    #pragma unroll
    for (int q = 0; q < 4; ++q) {
        f32x4 v = srow[q];
        #pragma unroll
        for (int j = 0; j < 4; ++j) tile[lr][lcg + q*4 + j] = v[j];
    }
    __syncthreads();
    int dc = tid >> 2, dkg = (tid & 3) * 16;
    u16x8 o0, o1;
    #pragma unroll
    for (int j = 0; j < 8; ++j) o0[j] = f2bf(tile[dkg + j][dc]);
    #pragma unroll
    for (int j = 0; j < 8; ++j) o1[j] = f2bf(tile[dkg + 8 + j][dc]);
    u16x8* drow = (u16x8*)(dst + (size_t)(c0 + dc) * 1024 + r0 + dkg);
    drow[0] = o0; drow[1] = o1;
}

// ---------------- gate: softmax + top2 + scatter; also emits xb (bf16 x) ----------------
__global__ __launch_bounds__(256) void kgate(const float* __restrict__ x, const float* __restrict__ gw,
                                             int* __restrict__ cnt, int* __restrict__ slotlist,
                                             float* __restrict__ wtlist, unsigned short* __restrict__ xb)
{
    int wid = threadIdx.x >> 6, lane = threadIdx.x & 63;
    int t = blockIdx.x * 4 + wid;
    const f32x4* xv = (const f32x4*)(x + (size_t)t * DIM + lane * 16);
    f32x4 xs0 = xv[0], xs1 = xv[1], xs2 = xv[2], xs3 = xv[3];
    float xr[16];
    #pragma unroll
    for (int j = 0; j < 4; ++j) { xr[j] = xs0[j]; xr[4+j] = xs1[j]; xr[8+j] = xs2[j]; xr[12+j] = xs3[j]; }

    // emit bf16 x row (fused former kconv_x)
    u16x8 o0, o1;
    #pragma unroll
    for (int j = 0; j < 8; ++j) o0[j] = f2bf(xr[j]);
    #pragma unroll
    for (int j = 0; j < 8; ++j) o1[j] = f2bf(xr[8 + j]);
    u16x8* xrow = (u16x8*)(xb + (size_t)t * DIM + lane * 16);
    xrow[0] = o0; xrow[1] = o1;

    float acc[8] = {0.f,0.f,0.f,0.f,0.f,0.f,0.f,0.f};
    #pragma unroll
    for (int i = 0; i < 16; ++i) {
        const f32x4* g = (const f32x4*)(gw + (size_t)(lane * 16 + i) * 8);
        f32x4 g0 = g[0], g1 = g[1];
        float xvv = xr[i];
        acc[0] += xvv * g0[0]; acc[1] += xvv * g0[1]; acc[2] += xvv * g0[2]; acc[3] += xvv * g0[3];
        acc[4] += xvv * g1[0]; acc[5] += xvv * g1[1]; acc[6] += xvv * g1[2]; acc[7] += xvv * g1[3];
    }
    #pragma unroll
    for (int e = 0; e < 8; ++e) {
        float v = acc[e];
        v += __shfl_xor(v, 1);  v += __shfl_xor(v, 2);  v += __shfl_xor(v, 4);
        v += __shfl_xor(v, 8);  v += __shfl_xor(v, 16); v += __shfl_xor(v, 32);
        acc[e] = v;
    }
    float mx = acc[0];
    #pragma unroll
    for (int e = 1; e < 8; ++e) mx = fmaxf(mx, acc[e]);
    float p[8]; float se = 0.f;
    #pragma unroll
    for (int e = 0; e < 8; ++e) { p[e] = expf(acc[e] - mx); se += p[e]; }
    float inv = 1.0f / se;
    int i0 = 0; float b0 = p[0];
    #pragma unroll
    for (int e = 1; e < 8; ++e) if (p[e] > b0) { b0 = p[e]; i0 = e; }
    int i1 = -1; float b1 = -1.f;
    #pragma unroll
    for (int e = 0; e < 8; ++e) if (e != i0 && p[e] > b1) { b1 = p[e]; i1 = e; }
    if (lane == 0) {
        int pos = atomicAdd(&cnt[i0], 1);
        slotlist[i0 * NT + pos] = t * 2;
        wtlist [i0 * NT + pos] = b0 * inv;
        pos = atomicAdd(&cnt[i1], 1);
        slotlist[i1 * NT + pos] = t * 2 + 1;
        wtlist [i1 * NT + pos] = b1 * inv;
    }
}

// ---------------- GEMM1: h = silu(X W1) * (X W3), gathered rows ----------------
// BM=128 BN=64 BK=64; 4 waves 2x2, wave tile 64x32 (dual acc for W1/W3)
// LDS: double-buffered, XOR-swizzled (pre-swizzled global source, swizzled ds_read)
__global__ __launch_bounds__(256) void kgemm1(
    const unsigned short* __restrict__ xb,
    const unsigned short* __restrict__ w1t, const unsigned short* __restrict__ w3t,
    const unsigned short* __restrict__ sw1t, const unsigned short* __restrict__ sw3t,
    const int* __restrict__ cnt, const int* __restrict__ slotlist,
    unsigned short* __restrict__ hbuf)
{
    int e = blockIdx.z;
    int m0 = blockIdx.y * 128;
    int n0 = blockIdx.x * 64;
    int n_rows = (e < 8) ? cnt[e] : NT;
    if (m0 >= n_rows) return;
    int rm = min(128, n_rows - m0);

    const unsigned short* b1p = (e < 8) ? (w1t + (size_t)e * DIM * INTER) : sw1t;
    const unsigned short* b3p = (e < 8) ? (w3t + (size_t)e * DIM * INTER) : sw3t;

    __shared__ __align__(16) short As[2][128 * 64];
    __shared__ __align__(16) short B1s[2][64 * 64];
    __shared__ __align__(16) short B3s[2][64 * 64];
    __shared__ int rowTok[128];
    __shared__ int rowSlot[128];

    int tid = threadIdx.x;
    if (tid < 128) {
        int r = m0 + min(tid, rm - 1);
        int slot, tok;
        if (e < 8) { slot = slotlist[e * NT + r]; tok = slot >> 1; }
        else       { tok = r; slot = 4096 + r; }
        rowTok[tid] = tok;
        rowSlot[tid] = slot;
    }
    __syncthreads();

    int wid = tid >> 6, lane = tid & 63;
    int wr = wid >> 1, wc = wid & 1;
    // staging source swizzle: LDS linear position (row, lane&7) gets global chunk (lane&7)^(row&7),
    // row&7 == lane>>3 for all our staging groups
    int swz_st = (((lane & 7) ^ (lane >> 3)) - (lane & 7)) * 16;  // delta vs natural chunk

    const char* gA[4];
    #pragma unroll
    for (int q = 0; q < 4; ++q) {
        int row = (q * 4 + wid) * 8 + (lane >> 3);
        gA[q] = (const char*)(xb + (size_t)rowTok[row] * DIM) + (lane & 7) * 16 + swz_st;
    }
    const char* gB1[2]; const char* gB3[2];
    #pragma unroll
    for (int q = 0; q < 2; ++q) {
        int nrow = (q * 4 + wid) * 8 + (lane >> 3);
        gB1[q] = (const char*)(b1p + (size_t)(n0 + nrow) * DIM) + (lane & 7) * 16 + swz_st;
        gB3[q] = (const char*)(b3p + (size_t)(n0 + nrow) * DIM) + (lane & 7) * 16 + swz_st;
    }

    f32x4 acc1[4][2], acc3[4][2];
    #pragma unroll
    for (int m = 0; m < 4; ++m)
        #pragma unroll
        for (int n = 0; n < 2; ++n) { acc1[m][n] = (f32x4){0.f,0.f,0.f,0.f}; acc3[m][n] = (f32x4){0.f,0.f,0.f,0.f}; }

    // prologue: stage tile 0 into buffer 0
    #pragma unroll
    for (int q = 0; q < 4; ++q) cp16(gA[q], &As[0][(q * 4 + wid) * 512]);
    #pragma unroll
    for (int q = 0; q < 2; ++q) {
        cp16(gB1[q], &B1s[0][(q * 4 + wid) * 512]);
        cp16(gB3[q], &B3s[0][(q * 4 + wid) * 512]);
    }
    __syncthreads();

    for (int t = 0; t < 16; ++t) {
        int cur = t & 1;
        if (t < 15) {   // prefetch next tile into the other buffer (overlaps compute below)
            size_t ko = (size_t)(t + 1) * 128;  // 64 k-elems * 2B
            #pragma unroll
            for (int q = 0; q < 4; ++q) cp16(gA[q] + ko, &As[cur ^ 1][(q * 4 + wid) * 512]);
            #pragma unroll
            for (int q = 0; q < 2; ++q) {
                cp16(gB1[q] + ko, &B1s[cur ^ 1][(q * 4 + wid) * 512]);
                cp16(gB3[q] + ko, &B3s[cur ^ 1][(q * 4 + wid) * 512]);
            }
        }
        #pragma unroll
        for (int ks = 0; ks < 2; ++ks) {
            int ch = (ks * 4 + (lane >> 4)) ^ (lane & 7);   // swizzled chunk
            s16x8 a[4];
            #pragma unroll
            for (int m = 0; m < 4; ++m) {
                int row = wr * 64 + m * 16 + (lane & 15);
                a[m] = *(const s16x8*)((const char*)&As[cur][0] + row * 128 + ch * 16);
            }
            #pragma unroll
            for (int n = 0; n < 2; ++n) {
                int col = wc * 32 + n * 16 + (lane & 15);
                s16x8 b1 = *(const s16x8*)((const char*)&B1s[cur][0] + col * 128 + ch * 16);
                s16x8 b3 = *(const s16x8*)((const char*)&B3s[cur][0] + col * 128 + ch * 16);
                #pragma unroll
                for (int m = 0; m < 4; ++m) {
                    acc1[m][n] = __builtin_amdgcn_mfma_f32_16x16x32_bf16(a[m], b1, acc1[m][n], 0, 0, 0);
                    acc3[m][n] = __builtin_amdgcn_mfma_f32_16x16x32_bf16(a[m], b3, acc3[m][n], 0, 0, 0);
                }
            }
        }
        __syncthreads();   // drains vmcnt(0)+lgkmcnt(0): next buffer staged, this buffer's reads done
    }

    #pragma unroll
    for (int m = 0; m < 4; ++m) {
        int rbase = wr * 64 + m * 16 + (lane >> 4) * 4;
        #pragma unroll
        for (int r = 0; r < 4; ++r) {
            int row = rbase + r;
            if (row < rm) {
                int hrow = rowSlot[row];
                #pragma unroll
                for (int n = 0; n < 2; ++n) {
                    float v1 = acc1[m][n][r], v3 = acc3[m][n][r];
                    float hv = (v1 / (1.0f + __expf(-v1))) * v3;
                    int col = n0 + wc * 32 + n * 16 + (lane & 15);
                    hbuf[(size_t)hrow * INTER + col] = f2bf(hv);
                }
            }
        }
    }
}

// ---------------- GEMM2: out += wt * (h W2), scatter by token ----------------
__global__ __launch_bounds__(256) void kgemm2(
    const unsigned short* __restrict__ hbuf,
    const unsigned short* __restrict__ w2t, const unsigned short* __restrict__ sw2t,
    const int* __restrict__ cnt, const int* __restrict__ slotlist, const float* __restrict__ wtlist,
    float* __restrict__ out)
{
    int e = blockIdx.z;
    int m0 = blockIdx.y * 128;
    int n0 = blockIdx.x * 64;
    int n_rows = (e < 8) ? cnt[e] : NT;
    if (m0 >= n_rows) return;
    int rm = min(128, n_rows - m0);
    const unsigned short* bp = (e < 8) ? (w2t + (size_t)e * DIM * INTER) : sw2t;

    __shared__ __align__(16) short As[2][128 * 64];
    __shared__ __align__(16) short Bs[2][64 * 64];
    __shared__ int rowTok[128];
    __shared__ int rowH[128];
    __shared__ float rowW[128];

    int tid = threadIdx.x;
    if (tid < 128) {
        int r = m0 + min(tid, rm - 1);
        if (e < 8) { int slot = slotlist[e * NT + r]; rowH[tid] = slot; rowTok[tid] = slot >> 1; rowW[tid] = wtlist[e * NT + r]; }
        else       { rowH[tid] = 4096 + r; rowTok[tid] = r; rowW[tid] = 1.0f; }
    }
    __syncthreads();

    int wid = tid >> 6, lane = tid & 63;
    int wr = wid >> 1, wc = wid & 1;
    int swz_st = (((lane & 7) ^ (lane >> 3)) - (lane & 7)) * 16;

    const char* gA[4];
    #pragma unroll
    for (int q = 0; q < 4; ++q) {
        int row = (q * 4 + wid) * 8 + (lane >> 3);
        gA[q] = (const char*)(hbuf + (size_t)rowH[row] * INTER) + (lane & 7) * 16 + swz_st;
    }
    const char* gB[2];
    #pragma unroll
    for (int q = 0; q < 2; ++q) {
        int nrow = (q * 4 + wid) * 8 + (lane >> 3);
        gB[q] = (const char*)(bp + (size_t)(n0 + nrow) * INTER) + (lane & 7) * 16 + swz_st;
    }

    f32x4 acc[4][2];
    #pragma unroll
    for (int m = 0; m < 4; ++m)
        #pragma unroll
        for (int n = 0; n < 2; ++n) acc[m][n] = (f32x4){0.f,0.f,0.f,0.f};

    #pragma unroll
    for (int q = 0; q < 4; ++q) cp16(gA[q], &As[0][(q * 4 + wid) * 512]);
    #pragma unroll
    for (int q = 0; q < 2; ++q) cp16(gB[q], &Bs[0][(q * 4 + wid) * 512]);
    __syncthreads();

    for (int t = 0; t < 16; ++t) {
        int cur = t & 1;
        if (t < 15) {
            size_t ko = (size_t)(t + 1) * 128;
            #pragma unroll
            for (int q = 0; q < 4; ++q) cp16(gA[q] + ko, &As[cur ^ 1][(q * 4 + wid) * 512]);
            #pragma unroll
            for (int q = 0; q < 2; ++q) cp16(gB[q] + ko, &Bs[cur ^ 1][(q * 4 + wid) * 512]);
        }
        #pragma unroll
        for (int ks = 0; ks < 2; ++ks) {
            int ch = (ks * 4 + (lane >> 4)) ^ (lane & 7);
            s16x8 a[4];
            #pragma unroll
            for (int m = 0; m < 4; ++m) {
                int row = wr * 64 + m * 16 + (lane & 15);
                a[m] = *(const s16x8*)((const char*)&As[cur][0] + row * 128 + ch * 16);
            }
            #pragma unroll
            for (int n = 0; n < 2; ++n) {
                int col = wc * 32 + n * 16 + (lane & 15);
                s16x8 b = *(const s16x8*)((const char*)&Bs[cur][0] + col * 128 + ch * 16);
                #pragma unroll
                for (int m = 0; m < 4; ++m)
                    acc[m][n] = __builtin_amdgcn_mfma_f32_16x16x32_bf16(a[m], b, acc[m][n], 0, 0, 0);
            }
        }
        __syncthreads();
    }

    #pragma unroll
    for (int m = 0; m < 4; ++m) {
        int rbase = wr * 64 + m * 16 + (lane >> 4) * 4;
        #pragma unroll
        for (int r = 0; r < 4; ++r) {
            int row = rbase + r;
            if (row < rm) {
                float wgt = rowW[row];
                int tok = rowTok[row];
                #pragma unroll
                for (int n = 0; n < 2; ++n) {
                    int col = n0 + wc * 32 + n * 16 + (lane & 15);
                    atomicAdd(&out[(size_t)tok * DIM + col], acc[m][n][r] * wgt);
                }
            }
        }
    }
}

extern "C" void kernel_launch(void* const* d_in, const int* in_sizes, int n_in,
                              void* d_out, int out_size, void* d_ws, size_t ws_size,
                              hipStream_t stream) {
    const float* x      = (const float*)d_in[0];
    const float* gate_w = (const float*)d_in[1];
    const float* w1     = (const float*)d_in[2];
    const float* w2     = (const float*)d_in[3];
    const float* w3     = (const float*)d_in[4];
    const float* sw1    = (const float*)d_in[5];
    const float* sw2    = (const float*)d_in[6];
    const float* sw3    = (const float*)d_in[7];
    float* out = (float*)d_out;

    if (ws_size < (size_t)WS_NEED) return;

    char* ws = (char*)d_ws;
    int*            cnt      = (int*)(ws + WS_CNT);
    int*            slotlist = (int*)(ws + WS_SLOT);
    float*          wtlist   = (float*)(ws + WS_WT);
    unsigned short* xb       = (unsigned short*)(ws + WS_XB);
    unsigned short* hbuf     = (unsigned short*)(ws + WS_H);
    unsigned short* w1t      = (unsigned short*)(ws + WS_W1T);
    unsigned short* w3t      = (unsigned short*)(ws + WS_W3T);
    unsigned short* w2t      = (unsigned short*)(ws + WS_W2T);
    unsigned short* sw1t     = (unsigned short*)(ws + WS_SW1T);
    unsigned short* sw3t     = (unsigned short*)(ws + WS_SW3T);
    unsigned short* sw2t     = (unsigned short*)(ws + WS_SW2T);

    hipMemsetAsync(cnt, 0, 256, stream);
    hipMemsetAsync(d_out, 0, (size_t)out_size * sizeof(float), stream);

    kconv_t<<<dim3(16, 16, 27), 256, 0, stream>>>(w1, w2, w3, sw1, sw2, sw3,
                                                  w1t, w3t, w2t, sw1t, sw3t, sw2t);
    kgate<<<dim3(NT / 4), 256, 0, stream>>>(x, gate_w, cnt, slotlist, wtlist, xb);
    kgemm1<<<dim3(16, 16, 9), 256, 0, stream>>>(xb, w1t, w3t, sw1t, sw3t, cnt, slotlist, hbuf);
    kgemm2<<<dim3(16, 16, 9), 256, 0, stream>>>(hbuf, w2t, sw2t, cnt, slotlist, wtlist, out);
}

// Round 4
// 156.756 us; speedup vs baseline: 1.2445x; 1.1584x over previous
//
#include <hip/hip_runtime.h>
#include <hip/hip_bf16.h>
#include <cstdint>
#include <cstddef>

#define DIM   1024
#define INTER 1024
#define NT    2048      // tokens
#define HROWS 6144      // 4096 routed pair slots + 2048 shared rows

typedef __attribute__((ext_vector_type(4))) float  f32x4;
typedef __attribute__((ext_vector_type(8))) short  s16x8;
typedef __attribute__((ext_vector_type(8))) unsigned short u16x8;

// workspace layout (bytes)
#define WS_CNT    0u          // cnt[0..7]=counts, cnt[8..16]=exclusive offsets
#define WS_SLOT   256u        // compacted slots[4096] (16 KB used of 64 KB)
#define WS_ASSIGN 33024u      // per-token packed experts [2048] int (8 KB)
#define WS_WT     65792u      // compacted wts[4096] (16 KB used of 64 KB)
#define WS_WTS2   98560u      // per-token float2 weights [2048] (16 KB)
#define WS_XB     131584u     // [2048][1024] bf16  (4 MB)
#define WS_H      4325888u    // [6144][1024] bf16  (12.6 MB)
#define WS_W1T    16908800u   // [8][1024][1024] bf16 (16 MB)
#define WS_W3T    33686016u
#define WS_W2T    50463232u
#define WS_SW1T   67240448u
#define WS_SW3T   69337600u
#define WS_SW2T   71434752u
#define WS_NEED   73531904u

__device__ __forceinline__ unsigned short f2bf(float f) {
    unsigned int u = __float_as_uint(f);
    return (unsigned short)((u + 0x7fffu + ((u >> 16) & 1u)) >> 16);
}

__device__ __forceinline__ void cp16(const void* g, void* l) {
    __builtin_amdgcn_global_load_lds((const __attribute__((address_space(1))) void*)g,
                                     (__attribute__((address_space(3))) void*)l, 16, 0, 0);
}

// ---------------- weight transpose + fp32->bf16 ----------------
__global__ __launch_bounds__(256) void kconv_t(
    const float* __restrict__ w1, const float* __restrict__ w2, const float* __restrict__ w3,
    const float* __restrict__ sw1, const float* __restrict__ sw2, const float* __restrict__ sw3,
    unsigned short* __restrict__ w1t, unsigned short* __restrict__ w3t, unsigned short* __restrict__ w2t,
    unsigned short* __restrict__ sw1t, unsigned short* __restrict__ sw3t, unsigned short* __restrict__ sw2t)
{
    int z = blockIdx.z;
    const float* src; unsigned short* dst;
    if (z < 8)        { src = w1  + (size_t)z      * DIM * INTER; dst = w1t  + (size_t)z      * DIM * INTER; }
    else if (z < 16)  { src = w3  + (size_t)(z-8)  * DIM * INTER; dst = w3t  + (size_t)(z-8)  * DIM * INTER; }
    else if (z < 24)  { src = w2  + (size_t)(z-16) * DIM * INTER; dst = w2t  + (size_t)(z-16) * DIM * INTER; }
    else if (z == 24) { src = sw1; dst = sw1t; }
    else if (z == 25) { src = sw3; dst = sw3t; }
    else              { src = sw2; dst = sw2t; }

    __shared__ float tile[64][65];
    int tid = threadIdx.x;
    int r0 = blockIdx.y * 64, c0 = blockIdx.x * 64;
    int lr = tid >> 2, lcg = (tid & 3) * 16;
    const f32x4* srow = (const f32x4*)(src + (size_t)(r0 + lr) * 1024 + c0 + lcg);
    #pragma unroll
    for (int q = 0; q < 4; ++q) {
        f32x4 v = srow[q];
        #pragma unroll
        for (int j = 0; j < 4; ++j) tile[lr][lcg + q*4 + j] = v[j];
    }
    __syncthreads();
    int dc = tid >> 2, dkg = (tid & 3) * 16;
    u16x8 o0, o1;
    #pragma unroll
    for (int j = 0; j < 8; ++j) o0[j] = f2bf(tile[dkg + j][dc]);
    #pragma unroll
    for (int j = 0; j < 8; ++j) o1[j] = f2bf(tile[dkg + 8 + j][dc]);
    u16x8* drow = (u16x8*)(dst + (size_t)(c0 + dc) * 1024 + r0 + dkg);
    drow[0] = o0; drow[1] = o1;
}

// ---------------- gate: softmax + top2, per-token dense output (no atomics) ----------------
// wave-per-token; lane l owns x elements {l, l+64, ..., l+960} so gw reads are wave-contiguous
__global__ __launch_bounds__(256) void kgate(const float* __restrict__ x, const float* __restrict__ gw,
                                             int* __restrict__ assign, float2* __restrict__ wts2,
                                             unsigned short* __restrict__ xb)
{
    int wid = threadIdx.x >> 6, lane = threadIdx.x & 63;
    int t = blockIdx.x * 4 + wid;
    const float* xrow = x + (size_t)t * DIM;

    float xr[16];
    float acc[8] = {0.f,0.f,0.f,0.f,0.f,0.f,0.f,0.f};
    #pragma unroll
    for (int j = 0; j < 16; ++j) {
        float xv = xrow[j * 64 + lane];
        xr[j] = xv;
        const f32x4* g = (const f32x4*)(gw + (size_t)(j * 64 + lane) * 8);
        f32x4 g0 = g[0], g1 = g[1];
        acc[0] += xv * g0[0]; acc[1] += xv * g0[1]; acc[2] += xv * g0[2]; acc[3] += xv * g0[3];
        acc[4] += xv * g1[0]; acc[5] += xv * g1[1]; acc[6] += xv * g1[2]; acc[7] += xv * g1[3];
    }
    // emit bf16 x (coalesced scalar stores)
    #pragma unroll
    for (int j = 0; j < 16; ++j) xb[(size_t)t * DIM + j * 64 + lane] = f2bf(xr[j]);

    #pragma unroll
    for (int e = 0; e < 8; ++e) {
        float v = acc[e];
        v += __shfl_xor(v, 1);  v += __shfl_xor(v, 2);  v += __shfl_xor(v, 4);
        v += __shfl_xor(v, 8);  v += __shfl_xor(v, 16); v += __shfl_xor(v, 32);
        acc[e] = v;
    }
    float mx = acc[0];
    #pragma unroll
    for (int e = 1; e < 8; ++e) mx = fmaxf(mx, acc[e]);
    float p[8]; float se = 0.f;
    #pragma unroll
    for (int e = 0; e < 8; ++e) { p[e] = expf(acc[e] - mx); se += p[e]; }
    float inv = 1.0f / se;
    int i0 = 0; float b0 = p[0];
    #pragma unroll
    for (int e = 1; e < 8; ++e) if (p[e] > b0) { b0 = p[e]; i0 = e; }
    int i1 = -1; float b1 = -1.f;
    #pragma unroll
    for (int e = 0; e < 8; ++e) if (e != i0 && p[e] > b1) { b1 = p[e]; i1 = e; }
    if (lane == 0) {
        assign[t] = i0 | (i1 << 8);
        wts2[t] = make_float2(b0 * inv, b1 * inv);
    }
}

// ---------------- scatter: build compacted per-expert lists (single block) ----------------
__global__ __launch_bounds__(256) void kscatter(const int* __restrict__ assign,
                                                const float2* __restrict__ wts2,
                                                int* __restrict__ cnt,      // [0..7] counts, [8..16] offsets
                                                int* __restrict__ slots,    // [4096]
                                                float* __restrict__ wts)    // [4096]
{
    __shared__ int h[8], pos[8];
    int tid = threadIdx.x, lane = tid & 63;
    if (tid < 8) h[tid] = 0;
    __syncthreads();

    // phase 1: histogram via ballot (few LDS atomics)
    for (int base = 0; base < NT; base += 256) {
        int a = assign[base + tid];
        int e0 = a & 255, e1 = (a >> 8) & 255;
        #pragma unroll
        for (int e = 0; e < 8; ++e) {
            unsigned long long m0 = __ballot(e0 == e);
            unsigned long long m1 = __ballot(e1 == e);
            if (lane == 0) {
                int c = __popcll(m0) + __popcll(m1);
                if (c) atomicAdd(&h[e], c);
            }
        }
    }
    __syncthreads();
    if (tid == 0) {
        int run = 0;
        #pragma unroll
        for (int e = 0; e < 8; ++e) {
            cnt[8 + e] = run; pos[e] = run;
            cnt[e] = h[e]; run += h[e];
        }
        cnt[16] = run;   // == 4096
    }
    __syncthreads();

    // phase 2: scatter with ballot-rank placement
    for (int base = 0; base < NT; base += 256) {
        int t = base + tid;
        int a = assign[t];
        float2 w = wts2[t];
        int e0 = a & 255, e1 = (a >> 8) & 255;
        unsigned long long lt = (1ull << lane) - 1ull;
        #pragma unroll
        for (int e = 0; e < 8; ++e) {
            unsigned long long m0 = __ballot(e0 == e);
            unsigned long long m1 = __ballot(e1 == e);
            int c = __popcll(m0) + __popcll(m1);
            int b = 0;
            if (lane == 0 && c) b = atomicAdd(&pos[e], c);
            b = __shfl(b, 0);
            if (e0 == e) { int r = __popcll(m0 & lt);                 slots[b + r] = t * 2;     wts[b + r] = w.x; }
            if (e1 == e) { int r = __popcll(m0) + __popcll(m1 & lt);  slots[b + r] = t * 2 + 1; wts[b + r] = w.y; }
        }
    }
}

// ---------------- GEMM1: h = silu(X W1) * (X W3), gathered rows ----------------
__global__ __launch_bounds__(256) void kgemm1(
    const unsigned short* __restrict__ xb,
    const unsigned short* __restrict__ w1t, const unsigned short* __restrict__ w3t,
    const unsigned short* __restrict__ sw1t, const unsigned short* __restrict__ sw3t,
    const int* __restrict__ cnt, const int* __restrict__ slots,
    unsigned short* __restrict__ hbuf)
{
    int e = blockIdx.z;
    int m0 = blockIdx.y * 128;
    int n0 = blockIdx.x * 64;
    int n_rows, lbase;
    if (e < 8) { n_rows = cnt[e]; lbase = cnt[8 + e]; } else { n_rows = NT; lbase = 0; }
    if (m0 >= n_rows) return;
    int rm = min(128, n_rows - m0);

    const unsigned short* b1p = (e < 8) ? (w1t + (size_t)e * DIM * INTER) : sw1t;
    const unsigned short* b3p = (e < 8) ? (w3t + (size_t)e * DIM * INTER) : sw3t;

    __shared__ __align__(16) short As[2][128 * 64];
    __shared__ __align__(16) short B1s[2][64 * 64];
    __shared__ __align__(16) short B3s[2][64 * 64];
    __shared__ int rowTok[128];
    __shared__ int rowSlot[128];

    int tid = threadIdx.x;
    if (tid < 128) {
        int r = m0 + min(tid, rm - 1);
        int slot, tok;
        if (e < 8) { slot = slots[lbase + r]; tok = slot >> 1; }
        else       { tok = r; slot = 4096 + r; }
        rowTok[tid] = tok;
        rowSlot[tid] = slot;
    }
    __syncthreads();

    int wid = tid >> 6, lane = tid & 63;
    int wr = wid >> 1, wc = wid & 1;
    int swz_st = (((lane & 7) ^ (lane >> 3)) - (lane & 7)) * 16;

    const char* gA[4];
    #pragma unroll
    for (int q = 0; q < 4; ++q) {
        int row = (q * 4 + wid) * 8 + (lane >> 3);
        gA[q] = (const char*)(xb + (size_t)rowTok[row] * DIM) + (lane & 7) * 16 + swz_st;
    }
    const char* gB1[2]; const char* gB3[2];
    #pragma unroll
    for (int q = 0; q < 2; ++q) {
        int nrow = (q * 4 + wid) * 8 + (lane >> 3);
        gB1[q] = (const char*)(b1p + (size_t)(n0 + nrow) * DIM) + (lane & 7) * 16 + swz_st;
        gB3[q] = (const char*)(b3p + (size_t)(n0 + nrow) * DIM) + (lane & 7) * 16 + swz_st;
    }

    f32x4 acc1[4][2], acc3[4][2];
    #pragma unroll
    for (int m = 0; m < 4; ++m)
        #pragma unroll
        for (int n = 0; n < 2; ++n) { acc1[m][n] = (f32x4){0.f,0.f,0.f,0.f}; acc3[m][n] = (f32x4){0.f,0.f,0.f,0.f}; }

    #pragma unroll
    for (int q = 0; q < 4; ++q) cp16(gA[q], &As[0][(q * 4 + wid) * 512]);
    #pragma unroll
    for (int q = 0; q < 2; ++q) {
        cp16(gB1[q], &B1s[0][(q * 4 + wid) * 512]);
        cp16(gB3[q], &B3s[0][(q * 4 + wid) * 512]);
    }
    __syncthreads();

    for (int t = 0; t < 16; ++t) {
        int cur = t & 1;
        if (t < 15) {
            size_t ko = (size_t)(t + 1) * 128;
            #pragma unroll
            for (int q = 0; q < 4; ++q) cp16(gA[q] + ko, &As[cur ^ 1][(q * 4 + wid) * 512]);
            #pragma unroll
            for (int q = 0; q < 2; ++q) {
                cp16(gB1[q] + ko, &B1s[cur ^ 1][(q * 4 + wid) * 512]);
                cp16(gB3[q] + ko, &B3s[cur ^ 1][(q * 4 + wid) * 512]);
            }
        }
        #pragma unroll
        for (int ks = 0; ks < 2; ++ks) {
            int ch = (ks * 4 + (lane >> 4)) ^ (lane & 7);
            s16x8 a[4];
            #pragma unroll
            for (int m = 0; m < 4; ++m) {
                int row = wr * 64 + m * 16 + (lane & 15);
                a[m] = *(const s16x8*)((const char*)&As[cur][0] + row * 128 + ch * 16);
            }
            #pragma unroll
            for (int n = 0; n < 2; ++n) {
                int col = wc * 32 + n * 16 + (lane & 15);
                s16x8 b1 = *(const s16x8*)((const char*)&B1s[cur][0] + col * 128 + ch * 16);
                s16x8 b3 = *(const s16x8*)((const char*)&B3s[cur][0] + col * 128 + ch * 16);
                #pragma unroll
                for (int m = 0; m < 4; ++m) {
                    acc1[m][n] = __builtin_amdgcn_mfma_f32_16x16x32_bf16(a[m], b1, acc1[m][n], 0, 0, 0);
                    acc3[m][n] = __builtin_amdgcn_mfma_f32_16x16x32_bf16(a[m], b3, acc3[m][n], 0, 0, 0);
                }
            }
        }
        __syncthreads();
    }

    #pragma unroll
    for (int m = 0; m < 4; ++m) {
        int rbase = wr * 64 + m * 16 + (lane >> 4) * 4;
        #pragma unroll
        for (int r = 0; r < 4; ++r) {
            int row = rbase + r;
            if (row < rm) {
                int hrow = rowSlot[row];
                #pragma unroll
                for (int n = 0; n < 2; ++n) {
                    float v1 = acc1[m][n][r], v3 = acc3[m][n][r];
                    float hv = (v1 / (1.0f + __expf(-v1))) * v3;
                    int col = n0 + wc * 32 + n * 16 + (lane & 15);
                    hbuf[(size_t)hrow * INTER + col] = f2bf(hv);
                }
            }
        }
    }
}

// ---------------- GEMM2: out += wt * (h W2), scatter by token ----------------
__global__ __launch_bounds__(256) void kgemm2(
    const unsigned short* __restrict__ hbuf,
    const unsigned short* __restrict__ w2t, const unsigned short* __restrict__ sw2t,
    const int* __restrict__ cnt, const int* __restrict__ slots, const float* __restrict__ wts,
    float* __restrict__ out)
{
    int e = blockIdx.z;
    int m0 = blockIdx.y * 128;
    int n0 = blockIdx.x * 64;
    int n_rows, lbase;
    if (e < 8) { n_rows = cnt[e]; lbase = cnt[8 + e]; } else { n_rows = NT; lbase = 0; }
    if (m0 >= n_rows) return;
    int rm = min(128, n_rows - m0);
    const unsigned short* bp = (e < 8) ? (w2t + (size_t)e * DIM * INTER) : sw2t;

    __shared__ __align__(16) short As[2][128 * 64];
    __shared__ __align__(16) short Bs[2][64 * 64];
    __shared__ int rowTok[128];
    __shared__ int rowH[128];
    __shared__ float rowW[128];

    int tid = threadIdx.x;
    if (tid < 128) {
        int r = m0 + min(tid, rm - 1);
        if (e < 8) { int slot = slots[lbase + r]; rowH[tid] = slot; rowTok[tid] = slot >> 1; rowW[tid] = wts[lbase + r]; }
        else       { rowH[tid] = 4096 + r; rowTok[tid] = r; rowW[tid] = 1.0f; }
    }
    __syncthreads();

    int wid = tid >> 6, lane = tid & 63;
    int wr = wid >> 1, wc = wid & 1;
    int swz_st = (((lane & 7) ^ (lane >> 3)) - (lane & 7)) * 16;

    const char* gA[4];
    #pragma unroll
    for (int q = 0; q < 4; ++q) {
        int row = (q * 4 + wid) * 8 + (lane >> 3);
        gA[q] = (const char*)(hbuf + (size_t)rowH[row] * INTER) + (lane & 7) * 16 + swz_st;
    }
    const char* gB[2];
    #pragma unroll
    for (int q = 0; q < 2; ++q) {
        int nrow = (q * 4 + wid) * 8 + (lane >> 3);
        gB[q] = (const char*)(bp + (size_t)(n0 + nrow) * INTER) + (lane & 7) * 16 + swz_st;
    }

    f32x4 acc[4][2];
    #pragma unroll
    for (int m = 0; m < 4; ++m)
        #pragma unroll
        for (int n = 0; n < 2; ++n) acc[m][n] = (f32x4){0.f,0.f,0.f,0.f};

    #pragma unroll
    for (int q = 0; q < 4; ++q) cp16(gA[q], &As[0][(q * 4 + wid) * 512]);
    #pragma unroll
    for (int q = 0; q < 2; ++q) cp16(gB[q], &Bs[0][(q * 4 + wid) * 512]);
    __syncthreads();

    for (int t = 0; t < 16; ++t) {
        int cur = t & 1;
        if (t < 15) {
            size_t ko = (size_t)(t + 1) * 128;
            #pragma unroll
            for (int q = 0; q < 4; ++q) cp16(gA[q] + ko, &As[cur ^ 1][(q * 4 + wid) * 512]);
            #pragma unroll
            for (int q = 0; q < 2; ++q) cp16(gB[q] + ko, &Bs[cur ^ 1][(q * 4 + wid) * 512]);
        }
        #pragma unroll
        for (int ks = 0; ks < 2; ++ks) {
            int ch = (ks * 4 + (lane >> 4)) ^ (lane & 7);
            s16x8 a[4];
            #pragma unroll
            for (int m = 0; m < 4; ++m) {
                int row = wr * 64 + m * 16 + (lane & 15);
                a[m] = *(const s16x8*)((const char*)&As[cur][0] + row * 128 + ch * 16);
            }
            #pragma unroll
            for (int n = 0; n < 2; ++n) {
                int col = wc * 32 + n * 16 + (lane & 15);
                s16x8 b = *(const s16x8*)((const char*)&Bs[cur][0] + col * 128 + ch * 16);
                #pragma unroll
                for (int m = 0; m < 4; ++m)
                    acc[m][n] = __builtin_amdgcn_mfma_f32_16x16x32_bf16(a[m], b, acc[m][n], 0, 0, 0);
            }
        }
        __syncthreads();
    }

    #pragma unroll
    for (int m = 0; m < 4; ++m) {
        int rbase = wr * 64 + m * 16 + (lane >> 4) * 4;
        #pragma unroll
        for (int r = 0; r < 4; ++r) {
            int row = rbase + r;
            if (row < rm) {
                float wgt = rowW[row];
                int tok = rowTok[row];
                #pragma unroll
                for (int n = 0; n < 2; ++n) {
                    int col = n0 + wc * 32 + n * 16 + (lane & 15);
                    atomicAdd(&out[(size_t)tok * DIM + col], acc[m][n][r] * wgt);
                }
            }
        }
    }
}

extern "C" void kernel_launch(void* const* d_in, const int* in_sizes, int n_in,
                              void* d_out, int out_size, void* d_ws, size_t ws_size,
                              hipStream_t stream) {
    const float* x      = (const float*)d_in[0];
    const float* gate_w = (const float*)d_in[1];
    const float* w1     = (const float*)d_in[2];
    const float* w2     = (const float*)d_in[3];
    const float* w3     = (const float*)d_in[4];
    const float* sw1    = (const float*)d_in[5];
    const float* sw2    = (const float*)d_in[6];
    const float* sw3    = (const float*)d_in[7];
    float* out = (float*)d_out;

    if (ws_size < (size_t)WS_NEED) return;

    char* ws = (char*)d_ws;
    int*            cnt      = (int*)(ws + WS_CNT);
    int*            slots    = (int*)(ws + WS_SLOT);
    int*            assign   = (int*)(ws + WS_ASSIGN);
    float*          wts      = (float*)(ws + WS_WT);
    float2*         wts2     = (float2*)(ws + WS_WTS2);
    unsigned short* xb       = (unsigned short*)(ws + WS_XB);
    unsigned short* hbuf     = (unsigned short*)(ws + WS_H);
    unsigned short* w1t      = (unsigned short*)(ws + WS_W1T);
    unsigned short* w3t      = (unsigned short*)(ws + WS_W3T);
    unsigned short* w2t      = (unsigned short*)(ws + WS_W2T);
    unsigned short* sw1t     = (unsigned short*)(ws + WS_SW1T);
    unsigned short* sw3t     = (unsigned short*)(ws + WS_SW3T);
    unsigned short* sw2t     = (unsigned short*)(ws + WS_SW2T);

    hipMemsetAsync(d_out, 0, (size_t)out_size * sizeof(float), stream);

    kconv_t<<<dim3(16, 16, 27), 256, 0, stream>>>(w1, w2, w3, sw1, sw2, sw3,
                                                  w1t, w3t, w2t, sw1t, sw3t, sw2t);
    kgate<<<dim3(NT / 4), 256, 0, stream>>>(x, gate_w, assign, wts2, xb);
    kscatter<<<dim3(1), 256, 0, stream>>>(assign, wts2, cnt, slots, wts);
    kgemm1<<<dim3(16, 16, 9), 256, 0, stream>>>(xb, w1t, w3t, sw1t, sw3t, cnt, slots, hbuf);
    kgemm2<<<dim3(16, 16, 9), 256, 0, stream>>>(hbuf, w2t, sw2t, cnt, slots, wts, out);
}

// Round 6
// 150.935 us; speedup vs baseline: 1.2925x; 1.0386x over previous
//
#include <hip/hip_runtime.h>
#include <hip/hip_bf16.h>
#include <cstdint>
#include <cstddef>

#define DIM   1024
#define INTER 1024
#define NT    2048      // tokens
#define HROWS 6144      // 4096 routed pair slots + 2048 shared rows

typedef __attribute__((ext_vector_type(4))) float  f32x4;
typedef __attribute__((ext_vector_type(8))) short  s16x8;
typedef __attribute__((ext_vector_type(8))) unsigned short u16x8;

// workspace layout (bytes)
#define WS_CNT    0u          // cnt[0..7]=counts, cnt[8..16]=exclusive offsets
#define WS_SLOT   256u        // compacted slots[4096]
#define WS_ASSIGN 33024u      // per-token packed experts [2048] int
#define WS_WT     65792u      // compacted wts[4096]
#define WS_WTS2   98560u      // per-token float2 weights [2048]
#define WS_XB     131584u     // [2048][1024] bf16  (4 MB)
#define WS_H      4325888u    // [6144][1024] bf16  (12.6 MB)
#define WS_W1T    16908800u   // [8][1024][1024] bf16 (16 MB)
#define WS_W3T    33686016u
#define WS_W2T    50463232u
#define WS_SW1T   67240448u
#define WS_SW3T   69337600u
#define WS_SW2T   71434752u
#define WS_NEED   73531904u

__device__ __forceinline__ unsigned short f2bf(float f) {
    unsigned int u = __float_as_uint(f);
    return (unsigned short)((u + 0x7fffu + ((u >> 16) & 1u)) >> 16);
}

__device__ __forceinline__ void cp16(const void* g, void* l) {
    __builtin_amdgcn_global_load_lds((const __attribute__((address_space(1))) void*)g,
                                     (__attribute__((address_space(3))) void*)l, 16, 0, 0);
}

// ---------------- weight transpose + fp32->bf16 ----------------
__global__ __launch_bounds__(256) void kconv_t(
    const float* __restrict__ w1, const float* __restrict__ w2, const float* __restrict__ w3,
    const float* __restrict__ sw1, const float* __restrict__ sw2, const float* __restrict__ sw3,
    unsigned short* __restrict__ w1t, unsigned short* __restrict__ w3t, unsigned short* __restrict__ w2t,
    unsigned short* __restrict__ sw1t, unsigned short* __restrict__ sw3t, unsigned short* __restrict__ sw2t)
{
    int z = blockIdx.z;
    const float* src; unsigned short* dst;
    if (z < 8)        { src = w1  + (size_t)z      * DIM * INTER; dst = w1t  + (size_t)z      * DIM * INTER; }
    else if (z < 16)  { src = w3  + (size_t)(z-8)  * DIM * INTER; dst = w3t  + (size_t)(z-8)  * DIM * INTER; }
    else if (z < 24)  { src = w2  + (size_t)(z-16) * DIM * INTER; dst = w2t  + (size_t)(z-16) * DIM * INTER; }
    else if (z == 24) { src = sw1; dst = sw1t; }
    else if (z == 25) { src = sw3; dst = sw3t; }
    else              { src = sw2; dst = sw2t; }

    __shared__ float tile[64][65];
    int tid = threadIdx.x;
    int r0 = blockIdx.y * 64, c0 = blockIdx.x * 64;
    int lr = tid >> 2, lcg = (tid & 3) * 16;
    const f32x4* srow = (const f32x4*)(src + (size_t)(r0 + lr) * 1024 + c0 + lcg);
    #pragma unroll
    for (int q = 0; q < 4; ++q) {
        f32x4 v = srow[q];
        #pragma unroll
        for (int j = 0; j < 4; ++j) tile[lr][lcg + q*4 + j] = v[j];
    }
    __syncthreads();
    int dc = tid >> 2, dkg = (tid & 3) * 16;
    u16x8 o0, o1;
    #pragma unroll
    for (int j = 0; j < 8; ++j) o0[j] = f2bf(tile[dkg + j][dc]);
    #pragma unroll
    for (int j = 0; j < 8; ++j) o1[j] = f2bf(tile[dkg + 8 + j][dc]);
    u16x8* drow = (u16x8*)(dst + (size_t)(c0 + dc) * 1024 + r0 + dkg);
    drow[0] = o0; drow[1] = o1;
}

// ---------------- gate: softmax + top2, per-token dense output (no atomics) ----------------
__global__ __launch_bounds__(256) void kgate(const float* __restrict__ x, const float* __restrict__ gw,
                                             int* __restrict__ assign, float2* __restrict__ wts2,
                                             unsigned short* __restrict__ xb)
{
    int wid = threadIdx.x >> 6, lane = threadIdx.x & 63;
    int t = blockIdx.x * 4 + wid;
    const float* xrow = x + (size_t)t * DIM;

    float xr[16];
    float acc[8] = {0.f,0.f,0.f,0.f,0.f,0.f,0.f,0.f};
    #pragma unroll
    for (int j = 0; j < 16; ++j) {
        float xv = xrow[j * 64 + lane];
        xr[j] = xv;
        const f32x4* g = (const f32x4*)(gw + (size_t)(j * 64 + lane) * 8);
        f32x4 g0 = g[0], g1 = g[1];
        acc[0] += xv * g0[0]; acc[1] += xv * g0[1]; acc[2] += xv * g0[2]; acc[3] += xv * g0[3];
        acc[4] += xv * g1[0]; acc[5] += xv * g1[1]; acc[6] += xv * g1[2]; acc[7] += xv * g1[3];
    }
    #pragma unroll
    for (int j = 0; j < 16; ++j) xb[(size_t)t * DIM + j * 64 + lane] = f2bf(xr[j]);

    #pragma unroll
    for (int e = 0; e < 8; ++e) {
        float v = acc[e];
        v += __shfl_xor(v, 1);  v += __shfl_xor(v, 2);  v += __shfl_xor(v, 4);
        v += __shfl_xor(v, 8);  v += __shfl_xor(v, 16); v += __shfl_xor(v, 32);
        acc[e] = v;
    }
    float mx = acc[0];
    #pragma unroll
    for (int e = 1; e < 8; ++e) mx = fmaxf(mx, acc[e]);
    float p[8]; float se = 0.f;
    #pragma unroll
    for (int e = 0; e < 8; ++e) { p[e] = expf(acc[e] - mx); se += p[e]; }
    float inv = 1.0f / se;
    int i0 = 0; float b0 = p[0];
    #pragma unroll
    for (int e = 1; e < 8; ++e) if (p[e] > b0) { b0 = p[e]; i0 = e; }
    int i1 = -1; float b1 = -1.f;
    #pragma unroll
    for (int e = 0; e < 8; ++e) if (e != i0 && p[e] > b1) { b1 = p[e]; i1 = e; }
    if (lane == 0) {
        assign[t] = i0 | (i1 << 8);
        wts2[t] = make_float2(b0 * inv, b1 * inv);
    }
}

// ---------------- scatter: build compacted per-expert lists (single block) ----------------
__global__ __launch_bounds__(256) void kscatter(const int* __restrict__ assign,
                                                const float2* __restrict__ wts2,
                                                int* __restrict__ cnt,
                                                int* __restrict__ slots,
                                                float* __restrict__ wts)
{
    __shared__ int h[8], pos[8];
    int tid = threadIdx.x, lane = tid & 63;
    if (tid < 8) h[tid] = 0;
    __syncthreads();

    for (int base = 0; base < NT; base += 256) {
        int a = assign[base + tid];
        int e0 = a & 255, e1 = (a >> 8) & 255;
        #pragma unroll
        for (int e = 0; e < 8; ++e) {
            unsigned long long m0 = __ballot(e0 == e);
            unsigned long long m1 = __ballot(e1 == e);
            if (lane == 0) {
                int c = __popcll(m0) + __popcll(m1);
                if (c) atomicAdd(&h[e], c);
            }
        }
    }
    __syncthreads();
    if (tid == 0) {
        int run = 0;
        #pragma unroll
        for (int e = 0; e < 8; ++e) {
            cnt[8 + e] = run; pos[e] = run;
            cnt[e] = h[e]; run += h[e];
        }
        cnt[16] = run;
    }
    __syncthreads();

    for (int base = 0; base < NT; base += 256) {
        int t = base + tid;
        int a = assign[t];
        float2 w = wts2[t];
        int e0 = a & 255, e1 = (a >> 8) & 255;
        unsigned long long lt = (1ull << lane) - 1ull;
        #pragma unroll
        for (int e = 0; e < 8; ++e) {
            unsigned long long m0 = __ballot(e0 == e);
            unsigned long long m1 = __ballot(e1 == e);
            int c = __popcll(m0) + __popcll(m1);
            int b = 0;
            if (lane == 0 && c) b = atomicAdd(&pos[e], c);
            b = __shfl(b, 0);
            if (e0 == e) { int r = __popcll(m0 & lt);                 slots[b + r] = t * 2;     wts[b + r] = w.x; }
            if (e1 == e) { int r = __popcll(m0) + __popcll(m1 & lt);  slots[b + r] = t * 2 + 1; wts[b + r] = w.y; }
        }
    }
}

// ---------------- GEMM1: h = silu(X W1) * (X W3), gathered rows ----------------
// BM=128 BN=64 BK=64; 4 waves 2x2, wave tile 64x32 (dual acc for W1/W3)
// Double-buffered LDS + counted-vmcnt pipeline (T4): prefetch loads stay in
// flight across barriers; per K-step this wave issues 8 global_load_lds, so
// waiting vmcnt(8) means "previous tile's 8 loads have landed".
__global__ __launch_bounds__(256) void kgemm1(
    const unsigned short* __restrict__ xb,
    const unsigned short* __restrict__ w1t, const unsigned short* __restrict__ w3t,
    const unsigned short* __restrict__ sw1t, const unsigned short* __restrict__ sw3t,
    const int* __restrict__ cnt, const int* __restrict__ slots,
    unsigned short* __restrict__ hbuf)
{
    int e = blockIdx.z;
    int m0 = blockIdx.y * 128;
    int n0 = blockIdx.x * 64;
    int n_rows, lbase;
    if (e < 8) { n_rows = cnt[e]; lbase = cnt[8 + e]; } else { n_rows = NT; lbase = 0; }
    if (m0 >= n_rows) return;
    int rm = min(128, n_rows - m0);

    const unsigned short* b1p = (e < 8) ? (w1t + (size_t)e * DIM * INTER) : sw1t;
    const unsigned short* b3p = (e < 8) ? (w3t + (size_t)e * DIM * INTER) : sw3t;

    __shared__ __align__(16) short As[2][128 * 64];
    __shared__ __align__(16) short B1s[2][64 * 64];
    __shared__ __align__(16) short B3s[2][64 * 64];
    __shared__ int rowTok[128];
    __shared__ int rowSlot[128];

    int tid = threadIdx.x;
    if (tid < 128) {
        int r = m0 + min(tid, rm - 1);
        int slot, tok;
        if (e < 8) { slot = slots[lbase + r]; tok = slot >> 1; }
        else       { tok = r; slot = 4096 + r; }
        rowTok[tid] = tok;
        rowSlot[tid] = slot;
    }
    __syncthreads();

    int wid = tid >> 6, lane = tid & 63;
    int wr = wid >> 1, wc = wid & 1;
    int swz_st = (((lane & 7) ^ (lane >> 3)) - (lane & 7)) * 16;

    const char* gA[4];
    #pragma unroll
    for (int q = 0; q < 4; ++q) {
        int row = (q * 4 + wid) * 8 + (lane >> 3);
        gA[q] = (const char*)(xb + (size_t)rowTok[row] * DIM) + (lane & 7) * 16 + swz_st;
    }
    const char* gB1[2]; const char* gB3[2];
    #pragma unroll
    for (int q = 0; q < 2; ++q) {
        int nrow = (q * 4 + wid) * 8 + (lane >> 3);
        gB1[q] = (const char*)(b1p + (size_t)(n0 + nrow) * DIM) + (lane & 7) * 16 + swz_st;
        gB3[q] = (const char*)(b3p + (size_t)(n0 + nrow) * DIM) + (lane & 7) * 16 + swz_st;
    }

    f32x4 acc1[4][2], acc3[4][2];
    #pragma unroll
    for (int m = 0; m < 4; ++m)
        #pragma unroll
        for (int n = 0; n < 2; ++n) { acc1[m][n] = (f32x4){0.f,0.f,0.f,0.f}; acc3[m][n] = (f32x4){0.f,0.f,0.f,0.f}; }

    // prologue: stage tile 0 into buffer 0 (8 loads in flight)
    #pragma unroll
    for (int q = 0; q < 4; ++q) cp16(gA[q], &As[0][(q * 4 + wid) * 512]);
    #pragma unroll
    for (int q = 0; q < 2; ++q) {
        cp16(gB1[q], &B1s[0][(q * 4 + wid) * 512]);
        cp16(gB3[q], &B3s[0][(q * 4 + wid) * 512]);
    }

    for (int t = 0; t < 16; ++t) {
        int cur = t & 1;
        if (t < 15) {   // issue next tile's 8 loads, then wait only for tile t's 8
            size_t ko = (size_t)(t + 1) * 128;
            #pragma unroll
            for (int q = 0; q < 4; ++q) cp16(gA[q] + ko, &As[cur ^ 1][(q * 4 + wid) * 512]);
            #pragma unroll
            for (int q = 0; q < 2; ++q) {
                cp16(gB1[q] + ko, &B1s[cur ^ 1][(q * 4 + wid) * 512]);
                cp16(gB3[q] + ko, &B3s[cur ^ 1][(q * 4 + wid) * 512]);
            }
            asm volatile("s_waitcnt vmcnt(8)" ::: "memory");
        } else {
            asm volatile("s_waitcnt vmcnt(0)" ::: "memory");
        }
        __builtin_amdgcn_sched_barrier(0);
        __builtin_amdgcn_s_barrier();          // all waves: tile t staged
        __builtin_amdgcn_sched_barrier(0);

        #pragma unroll
        for (int ks = 0; ks < 2; ++ks) {
            int ch = (ks * 4 + (lane >> 4)) ^ (lane & 7);
            s16x8 a[4];
            #pragma unroll
            for (int m = 0; m < 4; ++m) {
                int row = wr * 64 + m * 16 + (lane & 15);
                a[m] = *(const s16x8*)((const char*)&As[cur][0] + row * 128 + ch * 16);
            }
            #pragma unroll
            for (int n = 0; n < 2; ++n) {
                int col = wc * 32 + n * 16 + (lane & 15);
                s16x8 b1 = *(const s16x8*)((const char*)&B1s[cur][0] + col * 128 + ch * 16);
                s16x8 b3 = *(const s16x8*)((const char*)&B3s[cur][0] + col * 128 + ch * 16);
                #pragma unroll
                for (int m = 0; m < 4; ++m) {
                    acc1[m][n] = __builtin_amdgcn_mfma_f32_16x16x32_bf16(a[m], b1, acc1[m][n], 0, 0, 0);
                    acc3[m][n] = __builtin_amdgcn_mfma_f32_16x16x32_bf16(a[m], b3, acc3[m][n], 0, 0, 0);
                }
            }
        }
        __builtin_amdgcn_sched_barrier(0);
        __builtin_amdgcn_s_barrier();          // all waves done reading buf[cur]
        __builtin_amdgcn_sched_barrier(0);
    }

    #pragma unroll
    for (int m = 0; m < 4; ++m) {
        int rbase = wr * 64 + m * 16 + (lane >> 4) * 4;
        #pragma unroll
        for (int r = 0; r < 4; ++r) {
            int row = rbase + r;
            if (row < rm) {
                int hrow = rowSlot[row];
                #pragma unroll
                for (int n = 0; n < 2; ++n) {
                    float v1 = acc1[m][n][r], v3 = acc3[m][n][r];
                    float hv = (v1 / (1.0f + __expf(-v1))) * v3;
                    int col = n0 + wc * 32 + n * 16 + (lane & 15);
                    hbuf[(size_t)hrow * INTER + col] = f2bf(hv);
                }
            }
        }
    }
}

// ---------------- GEMM2: out += wt * (h W2), scatter by token ----------------
// Same counted-vmcnt pipeline; 6 loads per K-step -> vmcnt(6).
__global__ __launch_bounds__(256) void kgemm2(
    const unsigned short* __restrict__ hbuf,
    const unsigned short* __restrict__ w2t, const unsigned short* __restrict__ sw2t,
    const int* __restrict__ cnt, const int* __restrict__ slots, const float* __restrict__ wts,
    float* __restrict__ out)
{
    int e = blockIdx.z;
    int m0 = blockIdx.y * 128;
    int n0 = blockIdx.x * 64;
    int n_rows, lbase;
    if (e < 8) { n_rows = cnt[e]; lbase = cnt[8 + e]; } else { n_rows = NT; lbase = 0; }
    if (m0 >= n_rows) return;
    int rm = min(128, n_rows - m0);
    const unsigned short* bp = (e < 8) ? (w2t + (size_t)e * DIM * INTER) : sw2t;

    __shared__ __align__(16) short As[2][128 * 64];
    __shared__ __align__(16) short Bs[2][64 * 64];
    __shared__ int rowTok[128];
    __shared__ int rowH[128];
    __shared__ float rowW[128];

    int tid = threadIdx.x;
    if (tid < 128) {
        int r = m0 + min(tid, rm - 1);
        if (e < 8) { int slot = slots[lbase + r]; rowH[tid] = slot; rowTok[tid] = slot >> 1; rowW[tid] = wts[lbase + r]; }
        else       { rowH[tid] = 4096 + r; rowTok[tid] = r; rowW[tid] = 1.0f; }
    }
    __syncthreads();

    int wid = tid >> 6, lane = tid & 63;
    int wr = wid >> 1, wc = wid & 1;
    int swz_st = (((lane & 7) ^ (lane >> 3)) - (lane & 7)) * 16;

    const char* gA[4];
    #pragma unroll
    for (int q = 0; q < 4; ++q) {
        int row = (q * 4 + wid) * 8 + (lane >> 3);
        gA[q] = (const char*)(hbuf + (size_t)rowH[row] * INTER) + (lane & 7) * 16 + swz_st;
    }
    const char* gB[2];
    #pragma unroll
    for (int q = 0; q < 2; ++q) {
        int nrow = (q * 4 + wid) * 8 + (lane >> 3);
        gB[q] = (const char*)(bp + (size_t)(n0 + nrow) * INTER) + (lane & 7) * 16 + swz_st;
    }

    f32x4 acc[4][2];
    #pragma unroll
    for (int m = 0; m < 4; ++m)
        #pragma unroll
        for (int n = 0; n < 2; ++n) acc[m][n] = (f32x4){0.f,0.f,0.f,0.f};

    #pragma unroll
    for (int q = 0; q < 4; ++q) cp16(gA[q], &As[0][(q * 4 + wid) * 512]);
    #pragma unroll
    for (int q = 0; q < 2; ++q) cp16(gB[q], &Bs[0][(q * 4 + wid) * 512]);

    for (int t = 0; t < 16; ++t) {
        int cur = t & 1;
        if (t < 15) {
            size_t ko = (size_t)(t + 1) * 128;
            #pragma unroll
            for (int q = 0; q < 4; ++q) cp16(gA[q] + ko, &As[cur ^ 1][(q * 4 + wid) * 512]);
            #pragma unroll
            for (int q = 0; q < 2; ++q) cp16(gB[q] + ko, &Bs[cur ^ 1][(q * 4 + wid) * 512]);
            asm volatile("s_waitcnt vmcnt(6)" ::: "memory");
        } else {
            asm volatile("s_waitcnt vmcnt(0)" ::: "memory");
        }
        __builtin_amdgcn_sched_barrier(0);
        __builtin_amdgcn_s_barrier();
        __builtin_amdgcn_sched_barrier(0);

        #pragma unroll
        for (int ks = 0; ks < 2; ++ks) {
            int ch = (ks * 4 + (lane >> 4)) ^ (lane & 7);
            s16x8 a[4];
            #pragma unroll
            for (int m = 0; m < 4; ++m) {
                int row = wr * 64 + m * 16 + (lane & 15);
                a[m] = *(const s16x8*)((const char*)&As[cur][0] + row * 128 + ch * 16);
            }
            #pragma unroll
            for (int n = 0; n < 2; ++n) {
                int col = wc * 32 + n * 16 + (lane & 15);
                s16x8 b = *(const s16x8*)((const char*)&Bs[cur][0] + col * 128 + ch * 16);
                #pragma unroll
                for (int m = 0; m < 4; ++m)
                    acc[m][n] = __builtin_amdgcn_mfma_f32_16x16x32_bf16(a[m], b, acc[m][n], 0, 0, 0);
            }
        }
        __builtin_amdgcn_sched_barrier(0);
        __builtin_amdgcn_s_barrier();
        __builtin_amdgcn_sched_barrier(0);
    }

    #pragma unroll
    for (int m = 0; m < 4; ++m) {
        int rbase = wr * 64 + m * 16 + (lane >> 4) * 4;
        #pragma unroll
        for (int r = 0; r < 4; ++r) {
            int row = rbase + r;
            if (row < rm) {
                float wgt = rowW[row];
                int tok = rowTok[row];
                #pragma unroll
                for (int n = 0; n < 2; ++n) {
                    int col = n0 + wc * 32 + n * 16 + (lane & 15);
                    atomicAdd(&out[(size_t)tok * DIM + col], acc[m][n][r] * wgt);
                }
            }
        }
    }
}

extern "C" void kernel_launch(void* const* d_in, const int* in_sizes, int n_in,
                              void* d_out, int out_size, void* d_ws, size_t ws_size,
                              hipStream_t stream) {
    const float* x      = (const float*)d_in[0];
    const float* gate_w = (const float*)d_in[1];
    const float* w1     = (const float*)d_in[2];
    const float* w2     = (const float*)d_in[3];
    const float* w3     = (const float*)d_in[4];
    const float* sw1    = (const float*)d_in[5];
    const float* sw2    = (const float*)d_in[6];
    const float* sw3    = (const float*)d_in[7];
    float* out = (float*)d_out;

    if (ws_size < (size_t)WS_NEED) return;

    char* ws = (char*)d_ws;
    int*            cnt      = (int*)(ws + WS_CNT);
    int*            slots    = (int*)(ws + WS_SLOT);
    int*            assign   = (int*)(ws + WS_ASSIGN);
    float*          wts      = (float*)(ws + WS_WT);
    float2*         wts2     = (float2*)(ws + WS_WTS2);
    unsigned short* xb       = (unsigned short*)(ws + WS_XB);
    unsigned short* hbuf     = (unsigned short*)(ws + WS_H);
    unsigned short* w1t      = (unsigned short*)(ws + WS_W1T);
    unsigned short* w3t      = (unsigned short*)(ws + WS_W3T);
    unsigned short* w2t      = (unsigned short*)(ws + WS_W2T);
    unsigned short* sw1t     = (unsigned short*)(ws + WS_SW1T);
    unsigned short* sw3t     = (unsigned short*)(ws + WS_SW3T);
    unsigned short* sw2t     = (unsigned short*)(ws + WS_SW2T);

    hipMemsetAsync(d_out, 0, (size_t)out_size * sizeof(float), stream);

    kconv_t<<<dim3(16, 16, 27), 256, 0, stream>>>(w1, w2, w3, sw1, sw2, sw3,
                                                  w1t, w3t, w2t, sw1t, sw3t, sw2t);
    kgate<<<dim3(NT / 4), 256, 0, stream>>>(x, gate_w, assign, wts2, xb);
    kscatter<<<dim3(1), 256, 0, stream>>>(assign, wts2, cnt, slots, wts);
    kgemm1<<<dim3(16, 16, 9), 256, 0, stream>>>(xb, w1t, w3t, sw1t, sw3t, cnt, slots, hbuf);
    kgemm2<<<dim3(16, 16, 9), 256, 0, stream>>>(hbuf, w2t, sw2t, cnt, slots, wts, out);
}

// Round 7
// 138.095 us; speedup vs baseline: 1.4127x; 1.0930x over previous
//
#include <hip/hip_runtime.h>
#include <hip/hip_bf16.h>
#include <cstdint>
#include <cstddef>

#define DIM   1024
#define INTER 1024
#define NT    2048      // tokens

typedef __attribute__((ext_vector_type(4))) float  f32x4;
typedef __attribute__((ext_vector_type(8))) short  s16x8;
typedef __attribute__((ext_vector_type(8))) unsigned short u16x8;

// workspace layout (bytes)
#define WS_CNT    0u          // cnt[0..7]=counts, cnt[8..16]=exclusive offsets
#define WS_SLOT   256u        // compacted slots[4096]
#define WS_ASSIGN 33024u      // per-token packed experts [2048] int
#define WS_WT     65792u      // compacted wts[4096]
#define WS_WTS2   98560u      // per-token float2 weights [2048]
#define WS_XB     131584u     // [2048][1024] bf16  (4 MB)
#define WS_H      4325888u    // [6144][1024] bf16  (12.6 MB)
#define WS_W1T    16908800u   // [8][1024][1024] bf16 (16 MB); reused as obuf after kgemm1
#define WS_W3T    33686016u
#define WS_W2T    50463232u
#define WS_SW1T   67240448u
#define WS_SW3T   69337600u
#define WS_SW2T   71434752u
#define WS_NEED   73531904u
#define WS_OBUF   WS_W1T      // [6144][1024] bf16 (12.6 MB < 16 MB region)

__device__ __forceinline__ unsigned short f2bf(float f) {
    unsigned int u = __float_as_uint(f);
    return (unsigned short)((u + 0x7fffu + ((u >> 16) & 1u)) >> 16);
}
__device__ __forceinline__ float bf2f(unsigned short v) {
    return __uint_as_float(((unsigned int)v) << 16);
}

__device__ __forceinline__ void cp16(const void* g, void* l) {
    __builtin_amdgcn_global_load_lds((const __attribute__((address_space(1))) void*)g,
                                     (__attribute__((address_space(3))) void*)l, 16, 0, 0);
}

// ---------------- weight transpose + fp32->bf16 ----------------
__global__ __launch_bounds__(256) void kconv_t(
    const float* __restrict__ w1, const float* __restrict__ w2, const float* __restrict__ w3,
    const float* __restrict__ sw1, const float* __restrict__ sw2, const float* __restrict__ sw3,
    unsigned short* __restrict__ w1t, unsigned short* __restrict__ w3t, unsigned short* __restrict__ w2t,
    unsigned short* __restrict__ sw1t, unsigned short* __restrict__ sw3t, unsigned short* __restrict__ sw2t)
{
    int z = blockIdx.z;
    const float* src; unsigned short* dst;
    if (z < 8)        { src = w1  + (size_t)z      * DIM * INTER; dst = w1t  + (size_t)z      * DIM * INTER; }
    else if (z < 16)  { src = w3  + (size_t)(z-8)  * DIM * INTER; dst = w3t  + (size_t)(z-8)  * DIM * INTER; }
    else if (z < 24)  { src = w2  + (size_t)(z-16) * DIM * INTER; dst = w2t  + (size_t)(z-16) * DIM * INTER; }
    else if (z == 24) { src = sw1; dst = sw1t; }
    else if (z == 25) { src = sw3; dst = sw3t; }
    else              { src = sw2; dst = sw2t; }

    __shared__ float tile[64][65];
    int tid = threadIdx.x;
    int r0 = blockIdx.y * 64, c0 = blockIdx.x * 64;
    int lr = tid >> 2, lcg = (tid & 3) * 16;
    const f32x4* srow = (const f32x4*)(src + (size_t)(r0 + lr) * 1024 + c0 + lcg);
    #pragma unroll
    for (int q = 0; q < 4; ++q) {
        f32x4 v = srow[q];
        #pragma unroll
        for (int j = 0; j < 4; ++j) tile[lr][lcg + q*4 + j] = v[j];
    }
    __syncthreads();
    int dc = tid >> 2, dkg = (tid & 3) * 16;
    u16x8 o0, o1;
    #pragma unroll
    for (int j = 0; j < 8; ++j) o0[j] = f2bf(tile[dkg + j][dc]);
    #pragma unroll
    for (int j = 0; j < 8; ++j) o1[j] = f2bf(tile[dkg + 8 + j][dc]);
    u16x8* drow = (u16x8*)(dst + (size_t)(c0 + dc) * 1024 + r0 + dkg);
    drow[0] = o0; drow[1] = o1;
}

// ---------------- gate: softmax + top2, per-token dense output ----------------
__global__ __launch_bounds__(256) void kgate(const float* __restrict__ x, const float* __restrict__ gw,
                                             int* __restrict__ assign, float2* __restrict__ wts2,
                                             unsigned short* __restrict__ xb)
{
    int wid = threadIdx.x >> 6, lane = threadIdx.x & 63;
    int t = blockIdx.x * 4 + wid;
    const float* xrow = x + (size_t)t * DIM;

    float xr[16];
    float acc[8] = {0.f,0.f,0.f,0.f,0.f,0.f,0.f,0.f};
    #pragma unroll
    for (int j = 0; j < 16; ++j) {
        float xv = xrow[j * 64 + lane];
        xr[j] = xv;
        const f32x4* g = (const f32x4*)(gw + (size_t)(j * 64 + lane) * 8);
        f32x4 g0 = g[0], g1 = g[1];
        acc[0] += xv * g0[0]; acc[1] += xv * g0[1]; acc[2] += xv * g0[2]; acc[3] += xv * g0[3];
        acc[4] += xv * g1[0]; acc[5] += xv * g1[1]; acc[6] += xv * g1[2]; acc[7] += xv * g1[3];
    }
    #pragma unroll
    for (int j = 0; j < 16; ++j) xb[(size_t)t * DIM + j * 64 + lane] = f2bf(xr[j]);

    #pragma unroll
    for (int e = 0; e < 8; ++e) {
        float v = acc[e];
        v += __shfl_xor(v, 1);  v += __shfl_xor(v, 2);  v += __shfl_xor(v, 4);
        v += __shfl_xor(v, 8);  v += __shfl_xor(v, 16); v += __shfl_xor(v, 32);
        acc[e] = v;
    }
    float mx = acc[0];
    #pragma unroll
    for (int e = 1; e < 8; ++e) mx = fmaxf(mx, acc[e]);
    float p[8]; float se = 0.f;
    #pragma unroll
    for (int e = 0; e < 8; ++e) { p[e] = expf(acc[e] - mx); se += p[e]; }
    float inv = 1.0f / se;
    int i0 = 0; float b0 = p[0];
    #pragma unroll
    for (int e = 1; e < 8; ++e) if (p[e] > b0) { b0 = p[e]; i0 = e; }
    int i1 = -1; float b1 = -1.f;
    #pragma unroll
    for (int e = 0; e < 8; ++e) if (e != i0 && p[e] > b1) { b1 = p[e]; i1 = e; }
    if (lane == 0) {
        assign[t] = i0 | (i1 << 8);
        wts2[t] = make_float2(b0 * inv, b1 * inv);
    }
}

// ---------------- scatter: build compacted per-expert lists (single block) ----------------
__global__ __launch_bounds__(256) void kscatter(const int* __restrict__ assign,
                                                const float2* __restrict__ wts2,
                                                int* __restrict__ cnt,
                                                int* __restrict__ slots,
                                                float* __restrict__ wts)
{
    __shared__ int h[8], pos[8];
    int tid = threadIdx.x, lane = tid & 63;
    if (tid < 8) h[tid] = 0;
    __syncthreads();

    for (int base = 0; base < NT; base += 256) {
        int a = assign[base + tid];
        int e0 = a & 255, e1 = (a >> 8) & 255;
        #pragma unroll
        for (int e = 0; e < 8; ++e) {
            unsigned long long m0 = __ballot(e0 == e);
            unsigned long long m1 = __ballot(e1 == e);
            if (lane == 0) {
                int c = __popcll(m0) + __popcll(m1);
                if (c) atomicAdd(&h[e], c);
            }
        }
    }
    __syncthreads();
    if (tid == 0) {
        int run = 0;
        #pragma unroll
        for (int e = 0; e < 8; ++e) {
            cnt[8 + e] = run; pos[e] = run;
            cnt[e] = h[e]; run += h[e];
        }
        cnt[16] = run;
    }
    __syncthreads();

    for (int base = 0; base < NT; base += 256) {
        int t = base + tid;
        int a = assign[t];
        float2 w = wts2[t];
        int e0 = a & 255, e1 = (a >> 8) & 255;
        unsigned long long lt = (1ull << lane) - 1ull;
        #pragma unroll
        for (int e = 0; e < 8; ++e) {
            unsigned long long m0 = __ballot(e0 == e);
            unsigned long long m1 = __ballot(e1 == e);
            int c = __popcll(m0) + __popcll(m1);
            int b = 0;
            if (lane == 0 && c) b = atomicAdd(&pos[e], c);
            b = __shfl(b, 0);
            if (e0 == e) { int r = __popcll(m0 & lt);                 slots[b + r] = t * 2;     wts[b + r] = w.x; }
            if (e1 == e) { int r = __popcll(m0) + __popcll(m1 & lt);  slots[b + r] = t * 2 + 1; wts[b + r] = w.y; }
        }
    }
}

// ---------------- GEMM1: h = silu(X W1) * (X W3), gathered rows ----------------
// BM=128 BN=64 BK=64; 4 waves 2x2. K-loop unrolled x2 (buffer index compile-
// time) with hoisted per-lane LDS byte offsets -> near-zero per-iter VALU.
__global__ __launch_bounds__(256) void kgemm1(
    const unsigned short* __restrict__ xb,
    const unsigned short* __restrict__ w1t, const unsigned short* __restrict__ w3t,
    const unsigned short* __restrict__ sw1t, const unsigned short* __restrict__ sw3t,
    const int* __restrict__ cnt, const int* __restrict__ slots,
    unsigned short* __restrict__ hbuf)
{
    int e = blockIdx.z;
    int m0 = blockIdx.y * 128;
    int n0 = blockIdx.x * 64;
    int n_rows, lbase;
    if (e < 8) { n_rows = cnt[e]; lbase = cnt[8 + e]; } else { n_rows = NT; lbase = 0; }
    if (m0 >= n_rows) return;
    int rm = min(128, n_rows - m0);

    const unsigned short* b1p = (e < 8) ? (w1t + (size_t)e * DIM * INTER) : sw1t;
    const unsigned short* b3p = (e < 8) ? (w3t + (size_t)e * DIM * INTER) : sw3t;

    __shared__ __align__(16) short As[2][128 * 64];   // 32 KB
    __shared__ __align__(16) short B1s[2][64 * 64];   // 16 KB
    __shared__ __align__(16) short B3s[2][64 * 64];   // 16 KB
    __shared__ int rowTok[128];
    __shared__ int rowSlot[128];

    int tid = threadIdx.x;
    if (tid < 128) {
        int r = m0 + min(tid, rm - 1);
        int slot, tok;
        if (e < 8) { slot = slots[lbase + r]; tok = slot >> 1; }
        else       { tok = r; slot = 4096 + r; }
        rowTok[tid] = tok;
        rowSlot[tid] = slot;
    }
    __syncthreads();

    int wid = tid >> 6, lane = tid & 63;
    int wr = wid >> 1, wc = wid & 1;
    int swz_st = (((lane & 7) ^ (lane >> 3)) - (lane & 7)) * 16;

    const char* pA[4];
    #pragma unroll
    for (int q = 0; q < 4; ++q) {
        int row = (q * 4 + wid) * 8 + (lane >> 3);
        pA[q] = (const char*)(xb + (size_t)rowTok[row] * DIM) + (lane & 7) * 16 + swz_st;
    }
    const char* pB1[2]; const char* pB3[2];
    #pragma unroll
    for (int q = 0; q < 2; ++q) {
        int nrow = (q * 4 + wid) * 8 + (lane >> 3);
        pB1[q] = (const char*)(b1p + (size_t)(n0 + nrow) * DIM) + (lane & 7) * 16 + swz_st;
        pB3[q] = (const char*)(b3p + (size_t)(n0 + nrow) * DIM) + (lane & 7) * 16 + swz_st;
    }

    // hoisted per-lane LDS read byte-offsets (ks variants); bases are immediates
    int loA[2], loB[2];
    #pragma unroll
    for (int ks = 0; ks < 2; ++ks) {
        int ch = ((ks * 4) + (lane >> 4)) ^ (lane & 7);
        loA[ks] = (wr * 64 + (lane & 15)) * 128 + ch * 16;
        loB[ks] = (wc * 32 + (lane & 15)) * 128 + ch * 16;
    }

    f32x4 acc1[4][2], acc3[4][2];
    #pragma unroll
    for (int m = 0; m < 4; ++m)
        #pragma unroll
        for (int n = 0; n < 2; ++n) { acc1[m][n] = (f32x4){0.f,0.f,0.f,0.f}; acc3[m][n] = (f32x4){0.f,0.f,0.f,0.f}; }

    // prologue: stage tile 0 into buf 0; pointers advance to tile 1
    #pragma unroll
    for (int q = 0; q < 4; ++q) { cp16(pA[q], (char*)As + (q * 4 + wid) * 1024); pA[q] += 128; }
    #pragma unroll
    for (int q = 0; q < 2; ++q) {
        cp16(pB1[q], (char*)B1s + (q * 4 + wid) * 1024); pB1[q] += 128;
        cp16(pB3[q], (char*)B3s + (q * 4 + wid) * 1024); pB3[q] += 128;
    }

    for (int tt = 0; tt < 8; ++tt) {
        #pragma unroll
        for (int half = 0; half < 2; ++half) {
            if (half == 0 || tt < 7) {   // stage next tile into buf half^1
                #pragma unroll
                for (int q = 0; q < 4; ++q) {
                    cp16(pA[q], (char*)As + (half ^ 1) * 16384 + (q * 4 + wid) * 1024);
                    pA[q] += 128;
                }
                #pragma unroll
                for (int q = 0; q < 2; ++q) {
                    cp16(pB1[q], (char*)B1s + (half ^ 1) * 8192 + (q * 4 + wid) * 1024);
                    pB1[q] += 128;
                    cp16(pB3[q], (char*)B3s + (half ^ 1) * 8192 + (q * 4 + wid) * 1024);
                    pB3[q] += 128;
                }
                asm volatile("s_waitcnt vmcnt(8)" ::: "memory");
            } else {
                asm volatile("s_waitcnt vmcnt(0)" ::: "memory");
            }
            __builtin_amdgcn_sched_barrier(0);
            __builtin_amdgcn_s_barrier();
            __builtin_amdgcn_sched_barrier(0);

            #pragma unroll
            for (int ks = 0; ks < 2; ++ks) {
                s16x8 a[4];
                #pragma unroll
                for (int m = 0; m < 4; ++m)
                    a[m] = *(const s16x8*)((const char*)As + half * 16384 + m * 2048 + loA[ks]);
                #pragma unroll
                for (int n = 0; n < 2; ++n) {
                    s16x8 b1 = *(const s16x8*)((const char*)B1s + half * 8192 + n * 2048 + loB[ks]);
                    s16x8 b3 = *(const s16x8*)((const char*)B3s + half * 8192 + n * 2048 + loB[ks]);
                    #pragma unroll
                    for (int m = 0; m < 4; ++m) {
                        acc1[m][n] = __builtin_amdgcn_mfma_f32_16x16x32_bf16(a[m], b1, acc1[m][n], 0, 0, 0);
                        acc3[m][n] = __builtin_amdgcn_mfma_f32_16x16x32_bf16(a[m], b3, acc3[m][n], 0, 0, 0);
                    }
                }
            }
            __builtin_amdgcn_sched_barrier(0);
            __builtin_amdgcn_s_barrier();
            __builtin_amdgcn_sched_barrier(0);
        }
    }

    #pragma unroll
    for (int m = 0; m < 4; ++m) {
        int rbase = wr * 64 + m * 16 + (lane >> 4) * 4;
        #pragma unroll
        for (int r = 0; r < 4; ++r) {
            int row = rbase + r;
            if (row < rm) {
                int hrow = rowSlot[row];
                #pragma unroll
                for (int n = 0; n < 2; ++n) {
                    float v1 = acc1[m][n][r], v3 = acc3[m][n][r];
                    float hv = (v1 / (1.0f + __expf(-v1))) * v3;
                    int col = n0 + wc * 32 + n * 16 + (lane & 15);
                    hbuf[(size_t)hrow * INTER + col] = f2bf(hv);
                }
            }
        }
    }
}

// ---------------- GEMM2: obuf[slot] = h W2 (bf16 rows; no atomics) ----------------
__global__ __launch_bounds__(256) void kgemm2(
    const unsigned short* __restrict__ hbuf,
    const unsigned short* __restrict__ w2t, const unsigned short* __restrict__ sw2t,
    const int* __restrict__ cnt, const int* __restrict__ slots,
    unsigned short* __restrict__ obuf)
{
    int e = blockIdx.z;
    int m0 = blockIdx.y * 128;
    int n0 = blockIdx.x * 64;
    int n_rows, lbase;
    if (e < 8) { n_rows = cnt[e]; lbase = cnt[8 + e]; } else { n_rows = NT; lbase = 0; }
    if (m0 >= n_rows) return;
    int rm = min(128, n_rows - m0);
    const unsigned short* bp = (e < 8) ? (w2t + (size_t)e * DIM * INTER) : sw2t;

    __shared__ __align__(16) short As[2][128 * 64];
    __shared__ __align__(16) short Bs[2][64 * 64];
    __shared__ int rowH[128];

    int tid = threadIdx.x;
    if (tid < 128) {
        int r = m0 + min(tid, rm - 1);
        rowH[tid] = (e < 8) ? slots[lbase + r] : (4096 + r);
    }
    __syncthreads();

    int wid = tid >> 6, lane = tid & 63;
    int wr = wid >> 1, wc = wid & 1;
    int swz_st = (((lane & 7) ^ (lane >> 3)) - (lane & 7)) * 16;

    const char* pA[4];
    #pragma unroll
    for (int q = 0; q < 4; ++q) {
        int row = (q * 4 + wid) * 8 + (lane >> 3);
        pA[q] = (const char*)(hbuf + (size_t)rowH[row] * INTER) + (lane & 7) * 16 + swz_st;
    }
    const char* pB[2];
    #pragma unroll
    for (int q = 0; q < 2; ++q) {
        int nrow = (q * 4 + wid) * 8 + (lane >> 3);
        pB[q] = (const char*)(bp + (size_t)(n0 + nrow) * INTER) + (lane & 7) * 16 + swz_st;
    }

    int loA[2], loB[2];
    #pragma unroll
    for (int ks = 0; ks < 2; ++ks) {
        int ch = ((ks * 4) + (lane >> 4)) ^ (lane & 7);
        loA[ks] = (wr * 64 + (lane & 15)) * 128 + ch * 16;
        loB[ks] = (wc * 32 + (lane & 15)) * 128 + ch * 16;
    }

    f32x4 acc[4][2];
    #pragma unroll
    for (int m = 0; m < 4; ++m)
        #pragma unroll
        for (int n = 0; n < 2; ++n) acc[m][n] = (f32x4){0.f,0.f,0.f,0.f};

    #pragma unroll
    for (int q = 0; q < 4; ++q) { cp16(pA[q], (char*)As + (q * 4 + wid) * 1024); pA[q] += 128; }
    #pragma unroll
    for (int q = 0; q < 2; ++q) { cp16(pB[q], (char*)Bs + (q * 4 + wid) * 1024); pB[q] += 128; }

    for (int tt = 0; tt < 8; ++tt) {
        #pragma unroll
        for (int half = 0; half < 2; ++half) {
            if (half == 0 || tt < 7) {
                #pragma unroll
                for (int q = 0; q < 4; ++q) {
                    cp16(pA[q], (char*)As + (half ^ 1) * 16384 + (q * 4 + wid) * 1024);
                    pA[q] += 128;
                }
                #pragma unroll
                for (int q = 0; q < 2; ++q) {
                    cp16(pB[q], (char*)Bs + (half ^ 1) * 8192 + (q * 4 + wid) * 1024);
                    pB[q] += 128;
                }
                asm volatile("s_waitcnt vmcnt(6)" ::: "memory");
            } else {
                asm volatile("s_waitcnt vmcnt(0)" ::: "memory");
            }
            __builtin_amdgcn_sched_barrier(0);
            __builtin_amdgcn_s_barrier();
            __builtin_amdgcn_sched_barrier(0);

            #pragma unroll
            for (int ks = 0; ks < 2; ++ks) {
                s16x8 a[4];
                #pragma unroll
                for (int m = 0; m < 4; ++m)
                    a[m] = *(const s16x8*)((const char*)As + half * 16384 + m * 2048 + loA[ks]);
                #pragma unroll
                for (int n = 0; n < 2; ++n) {
                    s16x8 b = *(const s16x8*)((const char*)Bs + half * 8192 + n * 2048 + loB[ks]);
                    #pragma unroll
                    for (int m = 0; m < 4; ++m)
                        acc[m][n] = __builtin_amdgcn_mfma_f32_16x16x32_bf16(a[m], b, acc[m][n], 0, 0, 0);
                }
            }
            __builtin_amdgcn_sched_barrier(0);
            __builtin_amdgcn_s_barrier();
            __builtin_amdgcn_sched_barrier(0);
        }
    }

    #pragma unroll
    for (int m = 0; m < 4; ++m) {
        int rbase = wr * 64 + m * 16 + (lane >> 4) * 4;
        #pragma unroll
        for (int r = 0; r < 4; ++r) {
            int row = rbase + r;
            if (row < rm) {
                int orow = rowH[row];
                #pragma unroll
                for (int n = 0; n < 2; ++n) {
                    int col = n0 + wc * 32 + n * 16 + (lane & 15);
                    obuf[(size_t)orow * DIM + col] = f2bf(acc[m][n][r]);
                }
            }
        }
    }
}

// ---------------- combine: out[t] = w0*o[2t] + w1*o[2t+1] + o[4096+t] ----------------
__global__ __launch_bounds__(256) void kcombine(const unsigned short* __restrict__ obuf,
                                                const float2* __restrict__ wts2,
                                                float* __restrict__ out)
{
    int gid = blockIdx.x * 256 + threadIdx.x;
    int t = gid >> 7;
    int d0 = (gid & 127) * 8;
    float2 w = wts2[t];
    u16x8 r0 = *(const u16x8*)&obuf[(size_t)(2 * t)     * DIM + d0];
    u16x8 r1 = *(const u16x8*)&obuf[(size_t)(2 * t + 1) * DIM + d0];
    u16x8 rs = *(const u16x8*)&obuf[(size_t)(4096 + t)  * DIM + d0];
    f32x4 o0, o1;
    #pragma unroll
    for (int j = 0; j < 4; ++j) o0[j] = w.x * bf2f(r0[j]) + w.y * bf2f(r1[j]) + bf2f(rs[j]);
    #pragma unroll
    for (int j = 0; j < 4; ++j) o1[j] = w.x * bf2f(r0[4+j]) + w.y * bf2f(r1[4+j]) + bf2f(rs[4+j]);
    f32x4* dst = (f32x4*)&out[(size_t)t * DIM + d0];
    dst[0] = o0; dst[1] = o1;
}

extern "C" void kernel_launch(void* const* d_in, const int* in_sizes, int n_in,
                              void* d_out, int out_size, void* d_ws, size_t ws_size,
                              hipStream_t stream) {
    const float* x      = (const float*)d_in[0];
    const float* gate_w = (const float*)d_in[1];
    const float* w1     = (const float*)d_in[2];
    const float* w2     = (const float*)d_in[3];
    const float* w3     = (const float*)d_in[4];
    const float* sw1    = (const float*)d_in[5];
    const float* sw2    = (const float*)d_in[6];
    const float* sw3    = (const float*)d_in[7];
    float* out = (float*)d_out;

    if (ws_size < (size_t)WS_NEED) return;

    char* ws = (char*)d_ws;
    int*            cnt      = (int*)(ws + WS_CNT);
    int*            slots    = (int*)(ws + WS_SLOT);
    int*            assign   = (int*)(ws + WS_ASSIGN);
    float*          wts      = (float*)(ws + WS_WT);
    float2*         wts2     = (float2*)(ws + WS_WTS2);
    unsigned short* xb       = (unsigned short*)(ws + WS_XB);
    unsigned short* hbuf     = (unsigned short*)(ws + WS_H);
    unsigned short* w1t      = (unsigned short*)(ws + WS_W1T);
    unsigned short* w3t      = (unsigned short*)(ws + WS_W3T);
    unsigned short* w2t      = (unsigned short*)(ws + WS_W2T);
    unsigned short* sw1t     = (unsigned short*)(ws + WS_SW1T);
    unsigned short* sw3t     = (unsigned short*)(ws + WS_SW3T);
    unsigned short* sw2t     = (unsigned short*)(ws + WS_SW2T);
    unsigned short* obuf     = (unsigned short*)(ws + WS_OBUF);   // aliases w1t (dead after kgemm1)

    kconv_t<<<dim3(16, 16, 27), 256, 0, stream>>>(w1, w2, w3, sw1, sw2, sw3,
                                                  w1t, w3t, w2t, sw1t, sw3t, sw2t);
    kgate<<<dim3(NT / 4), 256, 0, stream>>>(x, gate_w, assign, wts2, xb);
    kscatter<<<dim3(1), 256, 0, stream>>>(assign, wts2, cnt, slots, wts);
    kgemm1<<<dim3(16, 16, 9), 256, 0, stream>>>(xb, w1t, w3t, sw1t, sw3t, cnt, slots, hbuf);
    kgemm2<<<dim3(16, 16, 9), 256, 0, stream>>>(hbuf, w2t, sw2t, cnt, slots, obuf);
    kcombine<<<dim3(NT * DIM / 8 / 256), 256, 0, stream>>>(obuf, wts2, out);
}

// Round 8
// 128.876 us; speedup vs baseline: 1.5138x; 1.0715x over previous
//
#include <hip/hip_runtime.h>
#include <hip/hip_bf16.h>
#include <cstdint>
#include <cstddef>

#define DIM   1024
#define INTER 1024
#define NT    2048      // tokens

typedef __attribute__((ext_vector_type(4))) float  f32x4;
typedef __attribute__((ext_vector_type(8))) short  s16x8;
typedef __attribute__((ext_vector_type(8))) unsigned short u16x8;

// workspace layout (bytes)
#define WS_CNT    0u          // cnt[0..7]=counts, cnt[8..16]=exclusive offsets
#define WS_SLOT   256u        // compacted slots[4096]
#define WS_ASSIGN 33024u      // per-token packed experts [2048] int
#define WS_WT     65792u      // compacted wts[4096]
#define WS_WTS2   98560u      // per-token float2 weights [2048]
#define WS_XB     131584u     // [2048][1024] bf16  (4 MB)
#define WS_H      4325888u    // [6144][1024] bf16  (12.6 MB)
#define WS_W1T    16908800u   // [8][1024][1024] bf16 (16 MB); reused as obuf after kgemm1
#define WS_W3T    33686016u
#define WS_W2T    50463232u
#define WS_SW1T   67240448u
#define WS_SW3T   69337600u
#define WS_SW2T   71434752u
#define WS_NEED   73531904u
#define WS_OBUF   WS_W1T      // [6144][1024] bf16 (12.6 MB < 16 MB region)

__device__ __forceinline__ unsigned short f2bf(float f) {
    unsigned int u = __float_as_uint(f);
    return (unsigned short)((u + 0x7fffu + ((u >> 16) & 1u)) >> 16);
}
__device__ __forceinline__ float bf2f(unsigned short v) {
    return __uint_as_float(((unsigned int)v) << 16);
}

__device__ __forceinline__ void cp16(const void* g, void* l) {
    __builtin_amdgcn_global_load_lds((const __attribute__((address_space(1))) void*)g,
                                     (__attribute__((address_space(3))) void*)l, 16, 0, 0);
}

// ---- shared conv body: transpose 64(r) x 128(c) fp32 tile -> bf16 [c][r] ----
// smem must hold 2*64*65*4 = 33280 bytes
__device__ __forceinline__ void conv_tile(const float* __restrict__ src,
                                          unsigned short* __restrict__ dst,
                                          int r0, int c0, char* smem)
{
    float (*tile)[64][65] = (float (*)[64][65])smem;
    int tid = threadIdx.x;
    int lr = tid >> 2, lcg = (tid & 3) * 16;
    #pragma unroll
    for (int h = 0; h < 2; ++h) {
        const f32x4* srow = (const f32x4*)(src + (size_t)(r0 + lr) * 1024 + c0 + h * 64 + lcg);
        #pragma unroll
        for (int q = 0; q < 4; ++q) {
            f32x4 v = srow[q];
            #pragma unroll
            for (int j = 0; j < 4; ++j) tile[h][lr][lcg + q * 4 + j] = v[j];
        }
    }
    __syncthreads();
    int dc = tid >> 2, dkg = (tid & 3) * 16;
    #pragma unroll
    for (int h = 0; h < 2; ++h) {
        u16x8 o0, o1;
        #pragma unroll
        for (int j = 0; j < 8; ++j) o0[j] = f2bf(tile[h][dkg + j][dc]);
        #pragma unroll
        for (int j = 0; j < 8; ++j) o1[j] = f2bf(tile[h][dkg + 8 + j][dc]);
        u16x8* drow = (u16x8*)(dst + (size_t)(c0 + h * 64 + dc) * 1024 + r0 + dkg);
        drow[0] = o0; drow[1] = o1;
    }
}

// ---------------- fat1: conv(w1,w3,sw1,sw3) [blocks 0..2303] + gate [2304..2815] ----------------
__global__ __launch_bounds__(256) void kfat1(
    const float* __restrict__ x, const float* __restrict__ gw,
    const float* __restrict__ w1, const float* __restrict__ w3,
    const float* __restrict__ sw1, const float* __restrict__ sw3,
    unsigned short* __restrict__ w1t, unsigned short* __restrict__ w3t,
    unsigned short* __restrict__ sw1t, unsigned short* __restrict__ sw3t,
    int* __restrict__ assign, float2* __restrict__ wts2, unsigned short* __restrict__ xb)
{
    __shared__ __align__(16) char smem[33280];
    int bid = blockIdx.x;
    if (bid < 2304) {
        int slab = bid >> 7, t = bid & 127;
        int r0 = (t >> 3) * 64, c0 = (t & 7) * 128;
        const float* src; unsigned short* dst;
        if (slab < 8)        { src = w1 + (size_t)slab * DIM * INTER;       dst = w1t + (size_t)slab * DIM * INTER; }
        else if (slab < 16)  { src = w3 + (size_t)(slab - 8) * DIM * INTER; dst = w3t + (size_t)(slab - 8) * DIM * INTER; }
        else if (slab == 16) { src = sw1; dst = sw1t; }
        else                 { src = sw3; dst = sw3t; }
        conv_tile(src, dst, r0, c0, smem);
        return;
    }
    // ---- gate ----
    int wid = threadIdx.x >> 6, lane = threadIdx.x & 63;
    int t = (bid - 2304) * 4 + wid;
    const float* xrow = x + (size_t)t * DIM;

    float xr[16];
    float acc[8] = {0.f,0.f,0.f,0.f,0.f,0.f,0.f,0.f};
    #pragma unroll
    for (int j = 0; j < 16; ++j) {
        float xv = xrow[j * 64 + lane];
        xr[j] = xv;
        const f32x4* g = (const f32x4*)(gw + (size_t)(j * 64 + lane) * 8);
        f32x4 g0 = g[0], g1 = g[1];
        acc[0] += xv * g0[0]; acc[1] += xv * g0[1]; acc[2] += xv * g0[2]; acc[3] += xv * g0[3];
        acc[4] += xv * g1[0]; acc[5] += xv * g1[1]; acc[6] += xv * g1[2]; acc[7] += xv * g1[3];
    }
    #pragma unroll
    for (int j = 0; j < 16; ++j) xb[(size_t)t * DIM + j * 64 + lane] = f2bf(xr[j]);

    #pragma unroll
    for (int e = 0; e < 8; ++e) {
        float v = acc[e];
        v += __shfl_xor(v, 1);  v += __shfl_xor(v, 2);  v += __shfl_xor(v, 4);
        v += __shfl_xor(v, 8);  v += __shfl_xor(v, 16); v += __shfl_xor(v, 32);
        acc[e] = v;
    }
    float mx = acc[0];
    #pragma unroll
    for (int e = 1; e < 8; ++e) mx = fmaxf(mx, acc[e]);
    float p[8]; float se = 0.f;
    #pragma unroll
    for (int e = 0; e < 8; ++e) { p[e] = expf(acc[e] - mx); se += p[e]; }
    float inv = 1.0f / se;
    int i0 = 0; float b0 = p[0];
    #pragma unroll
    for (int e = 1; e < 8; ++e) if (p[e] > b0) { b0 = p[e]; i0 = e; }
    int i1 = -1; float b1 = -1.f;
    #pragma unroll
    for (int e = 0; e < 8; ++e) if (e != i0 && p[e] > b1) { b1 = p[e]; i1 = e; }
    if (lane == 0) {
        assign[t] = i0 | (i1 << 8);
        wts2[t] = make_float2(b0 * inv, b1 * inv);
    }
}

// ---------------- scatter: build compacted per-expert lists (single block) ----------------
__global__ __launch_bounds__(256) void kscatter(const int* __restrict__ assign,
                                                const float2* __restrict__ wts2,
                                                int* __restrict__ cnt,
                                                int* __restrict__ slots,
                                                float* __restrict__ wts)
{
    __shared__ int h[8], pos[8];
    int tid = threadIdx.x, lane = tid & 63;
    if (tid < 8) h[tid] = 0;
    __syncthreads();

    for (int base = 0; base < NT; base += 256) {
        int a = assign[base + tid];
        int e0 = a & 255, e1 = (a >> 8) & 255;
        #pragma unroll
        for (int e = 0; e < 8; ++e) {
            unsigned long long m0 = __ballot(e0 == e);
            unsigned long long m1 = __ballot(e1 == e);
            if (lane == 0) {
                int c = __popcll(m0) + __popcll(m1);
                if (c) atomicAdd(&h[e], c);
            }
        }
    }
    __syncthreads();
    if (tid == 0) {
        int run = 0;
        #pragma unroll
        for (int e = 0; e < 8; ++e) {
            cnt[8 + e] = run; pos[e] = run;
            cnt[e] = h[e]; run += h[e];
        }
        cnt[16] = run;
    }
    __syncthreads();

    for (int base = 0; base < NT; base += 256) {
        int t = base + tid;
        int a = assign[t];
        float2 w = wts2[t];
        int e0 = a & 255, e1 = (a >> 8) & 255;
        unsigned long long lt = (1ull << lane) - 1ull;
        #pragma unroll
        for (int e = 0; e < 8; ++e) {
            unsigned long long m0 = __ballot(e0 == e);
            unsigned long long m1 = __ballot(e1 == e);
            int c = __popcll(m0) + __popcll(m1);
            int b = 0;
            if (lane == 0 && c) b = atomicAdd(&pos[e], c);
            b = __shfl(b, 0);
            if (e0 == e) { int r = __popcll(m0 & lt);                 slots[b + r] = t * 2;     wts[b + r] = w.x; }
            if (e1 == e) { int r = __popcll(m0) + __popcll(m1 & lt);  slots[b + r] = t * 2 + 1; wts[b + r] = w.y; }
        }
    }
}

// ---------------- fat2: GEMM1 (z<9) + conv(w2,sw2) (z>=9, x<8) ----------------
// GEMM1: BM=128 BN=64 BK=64; 4 waves 2x2; dbuf LDS + counted vmcnt; unroll x2.
__global__ __launch_bounds__(256) void kfat2(
    const unsigned short* __restrict__ xb,
    const unsigned short* __restrict__ w1t, const unsigned short* __restrict__ w3t,
    const unsigned short* __restrict__ sw1t, const unsigned short* __restrict__ sw3t,
    const int* __restrict__ cnt, const int* __restrict__ slots,
    unsigned short* __restrict__ hbuf,
    const float* __restrict__ w2, const float* __restrict__ sw2,
    unsigned short* __restrict__ w2t, unsigned short* __restrict__ sw2t)
{
    __shared__ __align__(16) char smem[66560];
    int z = blockIdx.z;
    if (z >= 9) {
        if (blockIdx.x >= 8) return;
        int slab = z - 9;
        const float* src; unsigned short* dst;
        if (slab < 8) { src = w2 + (size_t)slab * DIM * INTER; dst = w2t + (size_t)slab * DIM * INTER; }
        else          { src = sw2; dst = sw2t; }
        conv_tile(src, dst, blockIdx.y * 64, blockIdx.x * 128, smem);
        return;
    }

    int e = z;
    int m0 = blockIdx.y * 128;
    int n0 = blockIdx.x * 64;
    int n_rows, lbase;
    if (e < 8) { n_rows = cnt[e]; lbase = cnt[8 + e]; } else { n_rows = NT; lbase = 0; }
    if (m0 >= n_rows) return;
    int rm = min(128, n_rows - m0);

    const unsigned short* b1p = (e < 8) ? (w1t + (size_t)e * DIM * INTER) : sw1t;
    const unsigned short* b3p = (e < 8) ? (w3t + (size_t)e * DIM * INTER) : sw3t;

    char* sA  = smem;            // 2 x 16384
    char* sB1 = smem + 32768;    // 2 x 8192
    char* sB3 = smem + 49152;    // 2 x 8192
    int* rowTok  = (int*)(smem + 65536);
    int* rowSlot = (int*)(smem + 66048);

    int tid = threadIdx.x;
    if (tid < 128) {
        int r = m0 + min(tid, rm - 1);
        int slot, tok;
        if (e < 8) { slot = slots[lbase + r]; tok = slot >> 1; }
        else       { tok = r; slot = 4096 + r; }
        rowTok[tid] = tok;
        rowSlot[tid] = slot;
    }
    __syncthreads();

    int wid = tid >> 6, lane = tid & 63;
    int wr = wid >> 1, wc = wid & 1;
    int swz_st = (((lane & 7) ^ (lane >> 3)) - (lane & 7)) * 16;

    const char* pA[4];
    #pragma unroll
    for (int q = 0; q < 4; ++q) {
        int row = (q * 4 + wid) * 8 + (lane >> 3);
        pA[q] = (const char*)(xb + (size_t)rowTok[row] * DIM) + (lane & 7) * 16 + swz_st;
    }
    const char* pB1[2]; const char* pB3[2];
    #pragma unroll
    for (int q = 0; q < 2; ++q) {
        int nrow = (q * 4 + wid) * 8 + (lane >> 3);
        pB1[q] = (const char*)(b1p + (size_t)(n0 + nrow) * DIM) + (lane & 7) * 16 + swz_st;
        pB3[q] = (const char*)(b3p + (size_t)(n0 + nrow) * DIM) + (lane & 7) * 16 + swz_st;
    }

    int loA[2], loB[2];
    #pragma unroll
    for (int ks = 0; ks < 2; ++ks) {
        int ch = ((ks * 4) + (lane >> 4)) ^ (lane & 7);
        loA[ks] = (wr * 64 + (lane & 15)) * 128 + ch * 16;
        loB[ks] = (wc * 32 + (lane & 15)) * 128 + ch * 16;
    }

    f32x4 acc1[4][2], acc3[4][2];
    #pragma unroll
    for (int m = 0; m < 4; ++m)
        #pragma unroll
        for (int n = 0; n < 2; ++n) { acc1[m][n] = (f32x4){0.f,0.f,0.f,0.f}; acc3[m][n] = (f32x4){0.f,0.f,0.f,0.f}; }

    #pragma unroll
    for (int q = 0; q < 4; ++q) { cp16(pA[q], sA + (q * 4 + wid) * 1024); pA[q] += 128; }
    #pragma unroll
    for (int q = 0; q < 2; ++q) {
        cp16(pB1[q], sB1 + (q * 4 + wid) * 1024); pB1[q] += 128;
        cp16(pB3[q], sB3 + (q * 4 + wid) * 1024); pB3[q] += 128;
    }

    for (int tt = 0; tt < 8; ++tt) {
        #pragma unroll
        for (int half = 0; half < 2; ++half) {
            if (half == 0 || tt < 7) {
                #pragma unroll
                for (int q = 0; q < 4; ++q) {
                    cp16(pA[q], sA + (half ^ 1) * 16384 + (q * 4 + wid) * 1024);
                    pA[q] += 128;
                }
                #pragma unroll
                for (int q = 0; q < 2; ++q) {
                    cp16(pB1[q], sB1 + (half ^ 1) * 8192 + (q * 4 + wid) * 1024);
                    pB1[q] += 128;
                    cp16(pB3[q], sB3 + (half ^ 1) * 8192 + (q * 4 + wid) * 1024);
                    pB3[q] += 128;
                }
                asm volatile("s_waitcnt vmcnt(8)" ::: "memory");
            } else {
                asm volatile("s_waitcnt vmcnt(0)" ::: "memory");
            }
            __builtin_amdgcn_sched_barrier(0);
            __builtin_amdgcn_s_barrier();
            __builtin_amdgcn_sched_barrier(0);

            #pragma unroll
            for (int ks = 0; ks < 2; ++ks) {
                s16x8 a[4];
                #pragma unroll
                for (int m = 0; m < 4; ++m)
                    a[m] = *(const s16x8*)(sA + half * 16384 + m * 2048 + loA[ks]);
                #pragma unroll
                for (int n = 0; n < 2; ++n) {
                    s16x8 b1 = *(const s16x8*)(sB1 + half * 8192 + n * 2048 + loB[ks]);
                    s16x8 b3 = *(const s16x8*)(sB3 + half * 8192 + n * 2048 + loB[ks]);
                    #pragma unroll
                    for (int m = 0; m < 4; ++m) {
                        acc1[m][n] = __builtin_amdgcn_mfma_f32_16x16x32_bf16(a[m], b1, acc1[m][n], 0, 0, 0);
                        acc3[m][n] = __builtin_amdgcn_mfma_f32_16x16x32_bf16(a[m], b3, acc3[m][n], 0, 0, 0);
                    }
                }
            }
            __builtin_amdgcn_sched_barrier(0);
            __builtin_amdgcn_s_barrier();
            __builtin_amdgcn_sched_barrier(0);
        }
    }

    #pragma unroll
    for (int m = 0; m < 4; ++m) {
        int rbase = wr * 64 + m * 16 + (lane >> 4) * 4;
        #pragma unroll
        for (int r = 0; r < 4; ++r) {
            int row = rbase + r;
            if (row < rm) {
                int hrow = rowSlot[row];
                #pragma unroll
                for (int n = 0; n < 2; ++n) {
                    float v1 = acc1[m][n][r], v3 = acc3[m][n][r];
                    float hv = (v1 / (1.0f + __expf(-v1))) * v3;
                    int col = n0 + wc * 32 + n * 16 + (lane & 15);
                    hbuf[(size_t)hrow * INTER + col] = f2bf(hv);
                }
            }
        }
    }
}

// ---------------- GEMM2: obuf[slot] = h W2 (bf16 rows; no atomics) ----------------
__global__ __launch_bounds__(256) void kgemm2(
    const unsigned short* __restrict__ hbuf,
    const unsigned short* __restrict__ w2t, const unsigned short* __restrict__ sw2t,
    const int* __restrict__ cnt, const int* __restrict__ slots,
    unsigned short* __restrict__ obuf)
{
    int e = blockIdx.z;
    int m0 = blockIdx.y * 128;
    int n0 = blockIdx.x * 64;
    int n_rows, lbase;
    if (e < 8) { n_rows = cnt[e]; lbase = cnt[8 + e]; } else { n_rows = NT; lbase = 0; }
    if (m0 >= n_rows) return;
    int rm = min(128, n_rows - m0);
    const unsigned short* bp = (e < 8) ? (w2t + (size_t)e * DIM * INTER) : sw2t;

    __shared__ __align__(16) short As[2][128 * 64];
    __shared__ __align__(16) short Bs[2][64 * 64];
    __shared__ int rowH[128];

    int tid = threadIdx.x;
    if (tid < 128) {
        int r = m0 + min(tid, rm - 1);
        rowH[tid] = (e < 8) ? slots[lbase + r] : (4096 + r);
    }
    __syncthreads();

    int wid = tid >> 6, lane = tid & 63;
    int wr = wid >> 1, wc = wid & 1;
    int swz_st = (((lane & 7) ^ (lane >> 3)) - (lane & 7)) * 16;

    const char* pA[4];
    #pragma unroll
    for (int q = 0; q < 4; ++q) {
        int row = (q * 4 + wid) * 8 + (lane >> 3);
        pA[q] = (const char*)(hbuf + (size_t)rowH[row] * INTER) + (lane & 7) * 16 + swz_st;
    }
    const char* pB[2];
    #pragma unroll
    for (int q = 0; q < 2; ++q) {
        int nrow = (q * 4 + wid) * 8 + (lane >> 3);
        pB[q] = (const char*)(bp + (size_t)(n0 + nrow) * INTER) + (lane & 7) * 16 + swz_st;
    }

    int loA[2], loB[2];
    #pragma unroll
    for (int ks = 0; ks < 2; ++ks) {
        int ch = ((ks * 4) + (lane >> 4)) ^ (lane & 7);
        loA[ks] = (wr * 64 + (lane & 15)) * 128 + ch * 16;
        loB[ks] = (wc * 32 + (lane & 15)) * 128 + ch * 16;
    }

    f32x4 acc[4][2];
    #pragma unroll
    for (int m = 0; m < 4; ++m)
        #pragma unroll
        for (int n = 0; n < 2; ++n) acc[m][n] = (f32x4){0.f,0.f,0.f,0.f};

    #pragma unroll
    for (int q = 0; q < 4; ++q) { cp16(pA[q], (char*)As + (q * 4 + wid) * 1024); pA[q] += 128; }
    #pragma unroll
    for (int q = 0; q < 2; ++q) { cp16(pB[q], (char*)Bs + (q * 4 + wid) * 1024); pB[q] += 128; }

    for (int tt = 0; tt < 8; ++tt) {
        #pragma unroll
        for (int half = 0; half < 2; ++half) {
            if (half == 0 || tt < 7) {
                #pragma unroll
                for (int q = 0; q < 4; ++q) {
                    cp16(pA[q], (char*)As + (half ^ 1) * 16384 + (q * 4 + wid) * 1024);
                    pA[q] += 128;
                }
                #pragma unroll
                for (int q = 0; q < 2; ++q) {
                    cp16(pB[q], (char*)Bs + (half ^ 1) * 8192 + (q * 4 + wid) * 1024);
                    pB[q] += 128;
                }
                asm volatile("s_waitcnt vmcnt(6)" ::: "memory");
            } else {
                asm volatile("s_waitcnt vmcnt(0)" ::: "memory");
            }
            __builtin_amdgcn_sched_barrier(0);
            __builtin_amdgcn_s_barrier();
            __builtin_amdgcn_sched_barrier(0);

            #pragma unroll
            for (int ks = 0; ks < 2; ++ks) {
                s16x8 a[4];
                #pragma unroll
                for (int m = 0; m < 4; ++m)
                    a[m] = *(const s16x8*)((const char*)As + half * 16384 + m * 2048 + loA[ks]);
                #pragma unroll
                for (int n = 0; n < 2; ++n) {
                    s16x8 b = *(const s16x8*)((const char*)Bs + half * 8192 + n * 2048 + loB[ks]);
                    #pragma unroll
                    for (int m = 0; m < 4; ++m)
                        acc[m][n] = __builtin_amdgcn_mfma_f32_16x16x32_bf16(a[m], b, acc[m][n], 0, 0, 0);
                }
            }
            __builtin_amdgcn_sched_barrier(0);
            __builtin_amdgcn_s_barrier();
            __builtin_amdgcn_sched_barrier(0);
        }
    }

    #pragma unroll
    for (int m = 0; m < 4; ++m) {
        int rbase = wr * 64 + m * 16 + (lane >> 4) * 4;
        #pragma unroll
        for (int r = 0; r < 4; ++r) {
            int row = rbase + r;
            if (row < rm) {
                int orow = rowH[row];
                #pragma unroll
                for (int n = 0; n < 2; ++n) {
                    int col = n0 + wc * 32 + n * 16 + (lane & 15);
                    obuf[(size_t)orow * DIM + col] = f2bf(acc[m][n][r]);
                }
            }
        }
    }
}

// ---------------- combine: out[t] = w0*o[2t] + w1*o[2t+1] + o[4096+t] ----------------
__global__ __launch_bounds__(256) void kcombine(const unsigned short* __restrict__ obuf,
                                                const float2* __restrict__ wts2,
                                                float* __restrict__ out)
{
    int gid = blockIdx.x * 256 + threadIdx.x;
    int t = gid >> 7;
    int d0 = (gid & 127) * 8;
    float2 w = wts2[t];
    u16x8 r0 = *(const u16x8*)&obuf[(size_t)(2 * t)     * DIM + d0];
    u16x8 r1 = *(const u16x8*)&obuf[(size_t)(2 * t + 1) * DIM + d0];
    u16x8 rs = *(const u16x8*)&obuf[(size_t)(4096 + t)  * DIM + d0];
    f32x4 o0, o1;
    #pragma unroll
    for (int j = 0; j < 4; ++j) o0[j] = w.x * bf2f(r0[j]) + w.y * bf2f(r1[j]) + bf2f(rs[j]);
    #pragma unroll
    for (int j = 0; j < 4; ++j) o1[j] = w.x * bf2f(r0[4+j]) + w.y * bf2f(r1[4+j]) + bf2f(rs[4+j]);
    f32x4* dst = (f32x4*)&out[(size_t)t * DIM + d0];
    dst[0] = o0; dst[1] = o1;
}

extern "C" void kernel_launch(void* const* d_in, const int* in_sizes, int n_in,
                              void* d_out, int out_size, void* d_ws, size_t ws_size,
                              hipStream_t stream) {
    const float* x      = (const float*)d_in[0];
    const float* gate_w = (const float*)d_in[1];
    const float* w1     = (const float*)d_in[2];
    const float* w2     = (const float*)d_in[3];
    const float* w3     = (const float*)d_in[4];
    const float* sw1    = (const float*)d_in[5];
    const float* sw2    = (const float*)d_in[6];
    const float* sw3    = (const float*)d_in[7];
    float* out = (float*)d_out;

    if (ws_size < (size_t)WS_NEED) return;

    char* ws = (char*)d_ws;
    int*            cnt      = (int*)(ws + WS_CNT);
    int*            slots    = (int*)(ws + WS_SLOT);
    int*            assign   = (int*)(ws + WS_ASSIGN);
    float*          wts      = (float*)(ws + WS_WT);
    float2*         wts2     = (float2*)(ws + WS_WTS2);
    unsigned short* xb       = (unsigned short*)(ws + WS_XB);
    unsigned short* hbuf     = (unsigned short*)(ws + WS_H);
    unsigned short* w1t      = (unsigned short*)(ws + WS_W1T);
    unsigned short* w3t      = (unsigned short*)(ws + WS_W3T);
    unsigned short* w2t      = (unsigned short*)(ws + WS_W2T);
    unsigned short* sw1t     = (unsigned short*)(ws + WS_SW1T);
    unsigned short* sw3t     = (unsigned short*)(ws + WS_SW3T);
    unsigned short* sw2t     = (unsigned short*)(ws + WS_SW2T);
    unsigned short* obuf     = (unsigned short*)(ws + WS_OBUF);   // aliases w1t (dead after fat2)

    kfat1<<<dim3(2816), 256, 0, stream>>>(x, gate_w, w1, w3, sw1, sw3,
                                          w1t, w3t, sw1t, sw3t, assign, wts2, xb);
    kscatter<<<dim3(1), 256, 0, stream>>>(assign, wts2, cnt, slots, wts);
    kfat2<<<dim3(16, 16, 18), 256, 0, stream>>>(xb, w1t, w3t, sw1t, sw3t, cnt, slots, hbuf,
                                                w2, sw2, w2t, sw2t);
    kgemm2<<<dim3(16, 16, 9), 256, 0, stream>>>(hbuf, w2t, sw2t, cnt, slots, obuf);
    kcombine<<<dim3(1024), 256, 0, stream>>>(obuf, wts2, out);
}